// Round 5
// baseline (346.290 us; speedup 1.0000x reference)
//
#include <hip/hip_runtime.h>
#include <hip/hip_cooperative_groups.h>

namespace cg = cooperative_groups;

#define NF 160
#define NP 80
#define ND 64
#define NC 512
#define NV 81                  // stored v columns 0..80 (Hermitian half)
#define NPIXH (NF*NV)          // 12960
#define NPIXP 13056            // padded to 51*256
#define NXBLK 51
#define NJ NXBLK               // partial rows
#define CPB 16                 // candidates per virtual block
#define NBLK 256               // cooperative grid blocks (1 per CU)
#define NTHR 256
#define NTH (NBLK*NTHR)
#define TWO_PI 6.283185307179586f

// per-pixel precomputed parameter slots
#define IP_AR 0
#define IP_AI 1
#define IP_BR 2
#define IP_BI 3
#define IP_P  4
#define IP_Q  5
#define IP_R  6
#define IP_C2T 7
#define IP_S2T 8
#define IP_K  9
#define IP_CD0 10
#define IP_SD0 11
#define IP_CD1 12
#define IP_SD1 13
#define IP_TCD 14
#define IP_S0 15
#define IP_W  16
#define NPRM 17

__device__ __forceinline__ void rot(float& c, float& s, float stc, float sts) {
  float t1 = s * sts;
  float t2 = s * stc;
  float cn = fmaf(c, stc, -t1);
  s = fmaf(c, sts, t2);
  c = cn;
}

__device__ __forceinline__ void start_i_pow(int n, float& c, float& s) {
  switch (n & 3) {
    case 0: c = 1.f; s = 0.f; break;
    case 1: c = 0.f; s = 1.f; break;
    case 2: c = -1.f; s = 0.f; break;
    default: c = 0.f; s = -1.f; break;
  }
}

__global__ __launch_bounds__(256, 2) void k_mega(
    const float* __restrict__ patch, const float* __restrict__ gw,
    const float* __restrict__ delays, const float* __restrict__ kloss,
    const float* __restrict__ theta, const float* __restrict__ cand,
    float* __restrict__ out,
    float2* __restrict__ T, float2* __restrict__ Y,
    float4* __restrict__ Yk4, float* __restrict__ prm,
    float* __restrict__ partial, float2* __restrict__ G,
    int* __restrict__ bestIdx) {
  cg::grid_group grid = cg::this_grid();
  const int tid = blockIdx.x * NTHR + threadIdx.x;

  // ---- phase 1: fft_x — T[d][a][v] = sum_b yw[d,a,b] e^{-2pi i v(b-40)/160} ----
  for (int idx = tid; idx < ND * NP * NV; idx += NTH) {
    int v = idx % NV;
    int a = (idx / NV) % NP;
    int d = idx / (NV * NP);
    float c, s;
    start_i_pow(v, c, s);
    float stc, sts;
    sincosf(-TWO_PI * (float)v / (float)NF, &sts, &stc);
    const float* prow = patch + (size_t)(d * NP + a) * NP;
    const float* grow = gw + a * NP;
    float accR = 0.f, accI = 0.f;
#pragma unroll 4
    for (int b = 0; b < NP; ++b) {
      float f = prow[b] * grow[b];
      accR = fmaf(f, c, accR);
      accI = fmaf(f, s, accI);
      rot(c, s, stc, sts);
    }
    T[idx] = make_float2(accR, accI);
  }
  grid.sync();

  // ---- phase 2: fft_y — Y[d][u][v] = sum_a T[d][a][v] e^{-2pi i u(a-40)/160} ----
  for (int idx = tid; idx < ND * 40 * NV; idx += NTH) {
    int v = idx % NV;
    int ug = (idx / NV) % 40;
    int d = idx / (NV * 40);
    float c[4], s[4], aR[4], aI[4], stc[4], sts[4];
#pragma unroll
    for (int j = 0; j < 4; ++j) {
      int u = ug * 4 + j;
      start_i_pow(u, c[j], s[j]);
      sincosf(-TWO_PI * (float)u / (float)NF, &sts[j], &stc[j]);
      aR[j] = 0.f; aI[j] = 0.f;
    }
    const float2* Tb = T + (size_t)(d * NP) * NV + v;
#pragma unroll 4
    for (int a = 0; a < NP; ++a) {
      float2 t = Tb[(size_t)a * NV];
#pragma unroll
      for (int j = 0; j < 4; ++j) {
        aR[j] = fmaf(t.x, c[j], aR[j]);
        aR[j] = fmaf(-t.y, s[j], aR[j]);
        aI[j] = fmaf(t.x, s[j], aI[j]);
        aI[j] = fmaf(t.y, c[j], aI[j]);
        rot(c[j], s[j], stc[j], sts[j]);
      }
    }
#pragma unroll
    for (int j = 0; j < 4; ++j) {
      int u = ug * 4 + j;
      Y[((size_t)d * NF + u) * NV + v] = make_float2(aR[j], aI[j]);
    }
  }
  grid.sync();

  // ---- phase 3: prep — per-pixel moments + Yk4 packing ----
  for (int p = tid; p < NPIXP; p += NTH) {
    if (p >= NPIXH) {
#pragma unroll
      for (int jj = 0; jj < ND / 4; ++jj)
        Yk4[(size_t)jj * NPIXP + p] = make_float4(0.f, 0.f, 0.f, 0.f);
      prm[IP_AR * NPIXP + p] = 0.f;  prm[IP_AI * NPIXP + p] = 0.f;
      prm[IP_BR * NPIXP + p] = 0.f;  prm[IP_BI * NPIXP + p] = 0.f;
      prm[IP_P * NPIXP + p] = 1.f;   prm[IP_Q * NPIXP + p] = 0.f;
      prm[IP_R * NPIXP + p] = 1.f;   prm[IP_C2T * NPIXP + p] = 0.f;
      prm[IP_S2T * NPIXP + p] = 0.f; prm[IP_K * NPIXP + p] = 0.f;
      prm[IP_CD0 * NPIXP + p] = 1.f; prm[IP_SD0 * NPIXP + p] = 0.f;
      prm[IP_CD1 * NPIXP + p] = 1.f; prm[IP_SD1 * NPIXP + p] = 0.f;
      prm[IP_TCD * NPIXP + p] = 2.f; prm[IP_S0 * NPIXP + p] = 0.f;
      prm[IP_W * NPIXP + p] = 0.f;
      continue;
    }
    int u = p / NV, v = p % NV;
    float k = kloss[u * NF + v];
    float th = theta[((u + 80) % NF) * NF + ((v + 80) % NF)];
    float c2t = cosf(2.f * th), s2t = sinf(2.f * th);
    float w;
    if (v == 0 || v == 80) {
      if (u == 0 || u == 80) w = 1.f;
      else if (u < 80) w = 2.f;
      else w = 0.f;
    } else w = 2.f;
    float d0 = delays[0], d1 = delays[1];
    float sd0f, cd0f;
    sincosf(k * d0, &sd0f, &cd0f);
    float stc, sts;
    sincosf(k * (d1 - d0), &sts, &stc);
    float tcd = 2.f * stc;
    float cd = cd0f, sd = sd0f;
    float cd1s = 0.f, sd1s = 0.f;
    float Ar = 0.f, Ai = 0.f, Br = 0.f, Bi = 0.f, Pm = 0.f, Qm = 0.f, Rm = 0.f, S0 = 0.f;
    float yktmp[ND];
#pragma unroll
    for (int d = 0; d < ND; ++d) {
      if (d == 1) { cd1s = cd; sd1s = sd; }
      float2 y = Y[((size_t)d * NF + u) * NV + v];
      Ar = fmaf(y.x, cd, Ar);  Ai = fmaf(y.y, cd, Ai);
      Br = fmaf(y.x, sd, Br);  Bi = fmaf(y.y, sd, Bi);
      Pm = fmaf(cd, cd, Pm);  Qm = fmaf(cd, sd, Qm);  Rm = fmaf(sd, sd, Rm);
      float yk = sqrtf(fmaf(y.x, y.x, y.y * y.y)) * k;
      yktmp[d] = yk;
      S0 = fmaf(yk, yk, S0);
      rot(cd, sd, stc, sts);
    }
#pragma unroll
    for (int jj = 0; jj < ND / 4; ++jj)
      Yk4[(size_t)jj * NPIXP + p] = make_float4(yktmp[2 * jj], yktmp[63 - 2 * jj],
                                                yktmp[2 * jj + 1], yktmp[62 - 2 * jj]);
    prm[IP_AR * NPIXP + p] = Ar;   prm[IP_AI * NPIXP + p] = Ai;
    prm[IP_BR * NPIXP + p] = Br;   prm[IP_BI * NPIXP + p] = Bi;
    prm[IP_P * NPIXP + p] = Pm;    prm[IP_Q * NPIXP + p] = Qm;
    prm[IP_R * NPIXP + p] = Rm;    prm[IP_C2T * NPIXP + p] = c2t;
    prm[IP_S2T * NPIXP + p] = s2t; prm[IP_K * NPIXP + p] = k;
    prm[IP_CD0 * NPIXP + p] = cd0f; prm[IP_SD0 * NPIXP + p] = sd0f;
    prm[IP_CD1 * NPIXP + p] = cd1s; prm[IP_SD1 * NPIXP + p] = sd1s;
    prm[IP_TCD * NPIXP + p] = tcd; prm[IP_S0 * NPIXP + p] = S0;
    prm[IP_W * NPIXP + p] = w;
  }
  grid.sync();

  // ---- phase 4: cand — dual Chebyshev chains over virtual blocks ----
  {
    int wid = threadIdx.x >> 6;
    int lane = threadIdx.x & 63;
    __shared__ float sdata[CPB][4];
    for (int vb = blockIdx.x; vb < NXBLK * (NC / CPB); vb += NBLK) {
      int bx = vb % NXBLK;
      int by = vb / NXBLK;
      int p = bx * 256 + threadIdx.x;
      int c0 = by * CPB;
      float Ar = prm[IP_AR * NPIXP + p], Ai = prm[IP_AI * NPIXP + p];
      float Br = prm[IP_BR * NPIXP + p], Bi = prm[IP_BI * NPIXP + p];
      float Pm = prm[IP_P * NPIXP + p], Qm = prm[IP_Q * NPIXP + p], Rm = prm[IP_R * NPIXP + p];
      float c2t = prm[IP_C2T * NPIXP + p], s2t = prm[IP_S2T * NPIXP + p];
      float k = prm[IP_K * NPIXP + p];
      float cd0 = prm[IP_CD0 * NPIXP + p], sd0 = prm[IP_SD0 * NPIXP + p];
      float cd1 = prm[IP_CD1 * NPIXP + p], sd1 = prm[IP_SD1 * NPIXP + p];
      float tcd = prm[IP_TCD * NPIXP + p], S0 = prm[IP_S0 * NPIXP + p];
      float wgt = prm[IP_W * NPIXP + p];
      float4 yk[ND / 4];
#pragma unroll
      for (int jj = 0; jj < ND / 4; ++jj) yk[jj] = Yk4[(size_t)jj * NPIXP + p];
#pragma unroll
      for (int jj = 0; jj < ND / 4; ++jj)
        asm volatile("" : "+v"(yk[jj].x), "+v"(yk[jj].y), "+v"(yk[jj].z), "+v"(yk[jj].w));
      for (int ci = 0; ci < CPB; ++ci) {
        int c = c0 + ci;
        float dc = cand[c * 3 + 0], xx = cand[c * 3 + 1], yy = cand[c * 3 + 2];
        float w_ = fmaf(xx, c2t, fmaf(yy, s2t, dc));
        float kw = k * w_;
        float sw, cw;
        __sincosf(kw, &sw, &cw);
        float rr = fmaf(cw, Ar, sw * Br);
        float ri = fmaf(cw, Ai, sw * Bi);
        float lhs = fmaf(cw * cw, Pm, fmaf(2.f * cw * sw, Qm, sw * sw * Rm));
        float rabs = __builtin_amdgcn_sqrtf(fmaf(rr, rr, ri * ri));
        float rl = __builtin_amdgcn_rcpf(lhs);
        float e = fmaf(-lhs, rl, 1.f);
        rl = fmaf(rl, e, rl);
        float kX = k * rabs * rl;
        float t0 = cd0 * cw, u0 = sd0 * sw;
        float t1 = cd1 * cw, u1 = sd1 * sw;
        float Am1 = t0 + u0, Bm1 = t0 - u0;
        float Ac  = t1 + u1, Bc  = t1 - u1;
        float MA0 = yk[0].x * fabsf(Am1);
        float MB0 = yk[0].y * fabsf(Bm1);
        float MA1 = yk[0].z * fabsf(Ac);
        float MB1 = yk[0].w * fabsf(Bc);
#pragma unroll
        for (int jj = 1; jj < ND / 4; ++jj) {
          float An = fmaf(tcd, Ac, -Am1);
          float Bn = fmaf(tcd, Bc, -Bm1);
          MA0 = fmaf(yk[jj].x, fabsf(An), MA0);
          MB0 = fmaf(yk[jj].y, fabsf(Bn), MB0);
          float An2 = fmaf(tcd, An, -Ac);
          float Bn2 = fmaf(tcd, Bn, -Bc);
          MA1 = fmaf(yk[jj].z, fabsf(An2), MA1);
          MB1 = fmaf(yk[jj].w, fabsf(Bn2), MB1);
          Am1 = An; Ac = An2;
          Bm1 = Bn; Bc = Bn2;
        }
        float M = (MA0 + MA1) + (MB0 + MB1);
        float contrib = fmaf(kX * kX, lhs, fmaf(-2.f * kX, M, S0)) * wgt;
        for (int off = 32; off > 0; off >>= 1) contrib += __shfl_xor(contrib, off);
        if (lane == 0) sdata[ci][wid] = contrib;
      }
      __syncthreads();
      if (threadIdx.x < CPB) {
        int ci = threadIdx.x;
        float s = (sdata[ci][0] + sdata[ci][1]) + (sdata[ci][2] + sdata[ci][3]);
        partial[(size_t)bx * NC + c0 + ci] = s;
      }
      __syncthreads();
    }
  }
  grid.sync();

  // ---- phase 5: argmin (block 0; 2 candidates per thread) ----
  if (blockIdx.x == 0) {
    __shared__ float sl[NTHR];
    __shared__ int si[NTHR];
    int c1 = threadIdx.x, c2 = threadIdx.x + NTHR;
    float s1 = 0.f, s2 = 0.f;
#pragma unroll
    for (int j = 0; j < NJ; ++j) {
      s1 += partial[(size_t)j * NC + c1];
      s2 += partial[(size_t)j * NC + c2];
    }
    float l; int i;
    if (s2 < s1) { l = s2; i = c2; } else { l = s1; i = c1; }
    sl[threadIdx.x] = l; si[threadIdx.x] = i;
    __syncthreads();
    for (int off = 128; off > 0; off >>= 1) {
      if (threadIdx.x < off) {
        float l2 = sl[threadIdx.x + off]; int i2 = si[threadIdx.x + off];
        if (l2 < sl[threadIdx.x] || (l2 == sl[threadIdx.x] && i2 < si[threadIdx.x])) {
          sl[threadIdx.x] = l2; si[threadIdx.x] = i2;
        }
      }
      __syncthreads();
    }
    if (threadIdx.x == 0) {
      int bi = si[0];
      out[6400] = cand[bi * 3 + 0];
      out[6401] = cand[bi * 3 + 1];
      out[6402] = cand[bi * 3 + 2];
      out[6403] = sl[0] * (1.f / 1638400.f);
      *bestIdx = bi;
    }
  }
  grid.sync();

  // ---- phase 6: ifft_u — X row (Hermitian expand) -> LDS -> row DFT -> G ----
  {
    __shared__ float xr[NF], xi[NF];
    if (blockIdx.x < NF) {
      int u = blockIdx.x;
      int bi = *bestIdx;
      float dc = cand[bi * 3 + 0], xx = cand[bi * 3 + 1], yy = cand[bi * 3 + 2];
      int v = threadIdx.x;
      if (v < NF) {
        float sign = 1.f;
        int ph;
        if (v <= 80) {
          ph = u * NV + v;
        } else {
          int u2 = (NF - u) % NF;
          ph = u2 * NV + (NF - v);
          sign = -1.f;
        }
        float Ar = prm[IP_AR * NPIXP + ph], Ai = prm[IP_AI * NPIXP + ph];
        float Br = prm[IP_BR * NPIXP + ph], Bi = prm[IP_BI * NPIXP + ph];
        float Pm = prm[IP_P * NPIXP + ph], Qm = prm[IP_Q * NPIXP + ph], Rm = prm[IP_R * NPIXP + ph];
        float c2t = prm[IP_C2T * NPIXP + ph], s2t = prm[IP_S2T * NPIXP + ph];
        float k = prm[IP_K * NPIXP + ph];
        float w_ = fmaf(xx, c2t, fmaf(yy, s2t, dc));
        float sw, cw;
        sincosf(k * w_, &sw, &cw);
        float rr = fmaf(cw, Ar, sw * Br);
        float ri = fmaf(cw, Ai, sw * Bi);
        float lhs = fmaf(cw * cw, Pm, fmaf(2.f * cw * sw, Qm, sw * sw * Rm));
        xr[v] = rr / lhs;
        xi[v] = sign * ri / lhs;
      }
      __syncthreads();
      int b = threadIdx.x;
      if (b < NP) {
        int xb = (b + 120) % NF;
        float stc, sts;
        sincosf(TWO_PI * (float)xb / (float)NF, &sts, &stc);
        float c = 1.f, s = 0.f, accR = 0.f, accI = 0.f;
#pragma unroll 4
        for (int vv = 0; vv < NF; ++vv) {
          float xrv = xr[vv], xiv = xi[vv];
          accR = fmaf(xrv, c, accR); accR = fmaf(-xiv, s, accR);
          accI = fmaf(xrv, s, accI); accI = fmaf(xiv, c, accI);
          rot(c, s, stc, sts);
        }
        G[(size_t)u * NP + b] = make_float2(accR, accI);
      }
    }
  }
  grid.sync();

  // ---- phase 7: ifft_y — out[a][b] = Re(sum_u G[u][b] e^{+2pi i ya u/160})/25600 ----
  for (int idx = tid; idx < NP * NP; idx += NTH) {
    int b = idx % NP;
    int a = idx / NP;
    int ya = (a + 120) % NF;
    float stc, sts;
    sincosf(TWO_PI * (float)ya / (float)NF, &sts, &stc);
    float c = 1.f, s = 0.f, accR = 0.f;
#pragma unroll 4
    for (int u = 0; u < NF; ++u) {
      float2 g = G[(size_t)u * NP + b];
      accR = fmaf(g.x, c, accR);
      accR = fmaf(-g.y, s, accR);
      rot(c, s, stc, sts);
    }
    out[idx] = accR * (1.f / 25600.f);
  }
}

extern "C" void kernel_launch(void* const* d_in, const int* in_sizes, int n_in,
                              void* d_out, int out_size, void* d_ws, size_t ws_size,
                              hipStream_t stream) {
  (void)in_sizes; (void)n_in; (void)out_size; (void)ws_size;
  const float* patch  = (const float*)d_in[0];
  const float* gw     = (const float*)d_in[1];
  const float* delays = (const float*)d_in[2];
  const float* theta  = (const float*)d_in[4];
  const float* kloss  = (const float*)d_in[5];
  const float* cand   = (const float*)d_in[6];
  float* out = (float*)d_out;

  char* ws = (char*)d_ws;
  size_t off = 0;
  float2* Y = (float2*)(ws + off);      off += (size_t)ND * NF * NV * 8;     // 6,635,520
  float2* T = (float2*)(ws + off);      off += (size_t)ND * NP * NV * 8;     // 3,317,760
  float4* Yk4 = (float4*)(ws + off);    off += (size_t)(ND / 4) * NPIXP * 16;// 3,342,336
  float* prm = (float*)(ws + off);      off += (size_t)NPRM * NPIXP * 4;     //   887,808
  float* partial = (float*)(ws + off);  off += (size_t)NJ * NC * 4;          //   104,448
  float2* G = (float2*)(ws + off);      off += (size_t)NF * NP * 8;          //   102,400
  int* bestIdx = (int*)(ws + off);

  void* args[] = {
    (void*)&patch, (void*)&gw, (void*)&delays, (void*)&kloss, (void*)&theta,
    (void*)&cand, (void*)&out, (void*)&T, (void*)&Y, (void*)&Yk4,
    (void*)&prm, (void*)&partial, (void*)&G, (void*)&bestIdx
  };
  hipLaunchCooperativeKernel((const void*)k_mega, dim3(NBLK), dim3(NTHR),
                             args, 0, stream);
}

// Round 6
// 252.822 us; speedup vs baseline: 1.3697x; 1.3697x over previous
//
#include <hip/hip_runtime.h>

#define NF 160
#define NP 80
#define ND 64
#define NC 512
#define NV 81                  // stored v columns 0..80 (Hermitian half)
#define NPIXH (NF*NV)          // 12960
#define NPIXP 13056            // padded to 51*256
#define NXBLK 51
#define NJ NXBLK               // partial rows
#define CPB 16                 // candidates per virtual block
#define NBLK 512               // 2 blocks/CU guaranteed resident (launch_bounds(256,2))
#define NTHR 256
#define NTH (NBLK*NTHR)
#define NGRP 64                // barrier groups
#define GSZ (NBLK/NGRP)        // blocks per group = 8
#define TWO_PI 6.283185307179586f

// per-pixel precomputed parameter slots
#define IP_AR 0
#define IP_AI 1
#define IP_BR 2
#define IP_BI 3
#define IP_P  4
#define IP_Q  5
#define IP_R  6
#define IP_C2T 7
#define IP_S2T 8
#define IP_K  9
#define IP_CD0 10
#define IP_SD0 11
#define IP_CD1 12
#define IP_SD1 13
#define IP_TCD 14
#define IP_S0 15
#define IP_W  16
#define NPRM 17

__device__ __forceinline__ void rot(float& c, float& s, float stc, float sts) {
  float t1 = s * sts;
  float t2 = s * stc;
  float cn = fmaf(c, stc, -t1);
  s = fmaf(c, sts, t2);
  c = cn;
}

__device__ __forceinline__ void start_i_pow(int n, float& c, float& s) {
  switch (n & 3) {
    case 0: c = 1.f; s = 0.f; break;
    case 1: c = 0.f; s = 1.f; break;
    case 2: c = -1.f; s = 0.f; break;
    default: c = 0.f; s = -1.f; break;
  }
}

// Two-level grid barrier: 64 padded group counters -> root -> generation bump.
// Device-scope atomics; release fence before arrival, acquire fence after exit.
__device__ __forceinline__ void gbar(int* grp, int* root, int* gen) {
  __syncthreads();                         // drains vmcnt: all block stores in L2
  if (threadIdx.x == 0) {
    __threadfence();                       // release: write back L2 (cross-XCD)
    int g = __hip_atomic_load(gen, __ATOMIC_RELAXED, __HIP_MEMORY_SCOPE_AGENT);
    int* gc = grp + (blockIdx.x & (NGRP - 1)) * 16;   // 64B spacing
    int a = __hip_atomic_fetch_add(gc, 1, __ATOMIC_RELAXED, __HIP_MEMORY_SCOPE_AGENT);
    if (a == GSZ - 1) {
      __hip_atomic_store(gc, 0, __ATOMIC_RELAXED, __HIP_MEMORY_SCOPE_AGENT);
      int r = __hip_atomic_fetch_add(root, 1, __ATOMIC_RELAXED, __HIP_MEMORY_SCOPE_AGENT);
      if (r == NGRP - 1) {
        __hip_atomic_store(root, 0, __ATOMIC_RELAXED, __HIP_MEMORY_SCOPE_AGENT);
        __hip_atomic_fetch_add(gen, 1, __ATOMIC_RELEASE, __HIP_MEMORY_SCOPE_AGENT);
      }
    }
    while (__hip_atomic_load(gen, __ATOMIC_RELAXED, __HIP_MEMORY_SCOPE_AGENT) == g)
      __builtin_amdgcn_s_sleep(1);
    __threadfence();                       // acquire: invalidate stale caches
  }
  __syncthreads();
}

__global__ __launch_bounds__(256, 2) void k_mega(
    const float* __restrict__ patch, const float* __restrict__ gw,
    const float* __restrict__ delays, const float* __restrict__ kloss,
    const float* __restrict__ theta, const float* __restrict__ cand,
    float* __restrict__ out,
    float2* __restrict__ T, float2* __restrict__ Y,
    float4* __restrict__ Yk4, float* __restrict__ prm,
    float* __restrict__ partial, float2* __restrict__ G,
    int* __restrict__ bestIdx, int* __restrict__ bar) {
  int* grp = bar;
  int* root = bar + NGRP * 16;
  int* gen = bar + NGRP * 16 + 1;
  const int tid = blockIdx.x * NTHR + threadIdx.x;

  // ---- phase 1: fft_x — T[d][a][v] = sum_b yw[d,a,b] e^{-2pi i v(b-40)/160} ----
  for (int idx = tid; idx < ND * NP * NV; idx += NTH) {
    int v = idx % NV;
    int a = (idx / NV) % NP;
    int d = idx / (NV * NP);
    float c, s;
    start_i_pow(v, c, s);
    float stc, sts;
    sincosf(-TWO_PI * (float)v / (float)NF, &sts, &stc);
    const float* prow = patch + (size_t)(d * NP + a) * NP;
    const float* grow = gw + a * NP;
    float accR = 0.f, accI = 0.f;
#pragma unroll 4
    for (int b = 0; b < NP; ++b) {
      float f = prow[b] * grow[b];
      accR = fmaf(f, c, accR);
      accI = fmaf(f, s, accI);
      rot(c, s, stc, sts);
    }
    T[idx] = make_float2(accR, accI);
  }
  gbar(grp, root, gen);

  // ---- phase 2: fft_y — Y[d][u][v] = sum_a T[d][a][v] e^{-2pi i u(a-40)/160} ----
  for (int idx = tid; idx < ND * 40 * NV; idx += NTH) {
    int v = idx % NV;
    int ug = (idx / NV) % 40;
    int d = idx / (NV * 40);
    float c[4], s[4], aR[4], aI[4], stc[4], sts[4];
#pragma unroll
    for (int j = 0; j < 4; ++j) {
      int u = ug * 4 + j;
      start_i_pow(u, c[j], s[j]);
      sincosf(-TWO_PI * (float)u / (float)NF, &sts[j], &stc[j]);
      aR[j] = 0.f; aI[j] = 0.f;
    }
    const float2* Tb = T + (size_t)(d * NP) * NV + v;
#pragma unroll 4
    for (int a = 0; a < NP; ++a) {
      float2 t = Tb[(size_t)a * NV];
#pragma unroll
      for (int j = 0; j < 4; ++j) {
        aR[j] = fmaf(t.x, c[j], aR[j]);
        aR[j] = fmaf(-t.y, s[j], aR[j]);
        aI[j] = fmaf(t.x, s[j], aI[j]);
        aI[j] = fmaf(t.y, c[j], aI[j]);
        rot(c[j], s[j], stc[j], sts[j]);
      }
    }
#pragma unroll
    for (int j = 0; j < 4; ++j) {
      int u = ug * 4 + j;
      Y[((size_t)d * NF + u) * NV + v] = make_float2(aR[j], aI[j]);
    }
  }
  gbar(grp, root, gen);

  // ---- phase 3: prep — per-pixel moments + Yk4 packing (wave-chunk spread) ----
  {
    int w = threadIdx.x >> 6;
    int lane = threadIdx.x & 63;
    int cch = blockIdx.x + NBLK * w;      // chunk id, block-major spread
    if (cch < NPIXP / 64) {               // 204 chunks
      int p = cch * 64 + lane;
      if (p >= NPIXH) {
#pragma unroll
        for (int jj = 0; jj < ND / 4; ++jj)
          Yk4[(size_t)jj * NPIXP + p] = make_float4(0.f, 0.f, 0.f, 0.f);
        prm[IP_AR * NPIXP + p] = 0.f;  prm[IP_AI * NPIXP + p] = 0.f;
        prm[IP_BR * NPIXP + p] = 0.f;  prm[IP_BI * NPIXP + p] = 0.f;
        prm[IP_P * NPIXP + p] = 1.f;   prm[IP_Q * NPIXP + p] = 0.f;
        prm[IP_R * NPIXP + p] = 1.f;   prm[IP_C2T * NPIXP + p] = 0.f;
        prm[IP_S2T * NPIXP + p] = 0.f; prm[IP_K * NPIXP + p] = 0.f;
        prm[IP_CD0 * NPIXP + p] = 1.f; prm[IP_SD0 * NPIXP + p] = 0.f;
        prm[IP_CD1 * NPIXP + p] = 1.f; prm[IP_SD1 * NPIXP + p] = 0.f;
        prm[IP_TCD * NPIXP + p] = 2.f; prm[IP_S0 * NPIXP + p] = 0.f;
        prm[IP_W * NPIXP + p] = 0.f;
      } else {
        int u = p / NV, v = p % NV;
        float k = kloss[u * NF + v];
        float th = theta[((u + 80) % NF) * NF + ((v + 80) % NF)];
        float c2t = cosf(2.f * th), s2t = sinf(2.f * th);
        float w_;
        if (v == 0 || v == 80) {
          if (u == 0 || u == 80) w_ = 1.f;
          else if (u < 80) w_ = 2.f;
          else w_ = 0.f;
        } else w_ = 2.f;
        float d0 = delays[0], d1 = delays[1];
        float sd0f, cd0f;
        sincosf(k * d0, &sd0f, &cd0f);
        float stc, sts;
        sincosf(k * (d1 - d0), &sts, &stc);
        float tcd = 2.f * stc;
        float cd = cd0f, sd = sd0f;
        float cd1s = 0.f, sd1s = 0.f;
        float Ar = 0.f, Ai = 0.f, Br = 0.f, Bi = 0.f, Pm = 0.f, Qm = 0.f, Rm = 0.f, S0 = 0.f;
        float yktmp[ND];
#pragma unroll
        for (int d = 0; d < ND; ++d) {
          if (d == 1) { cd1s = cd; sd1s = sd; }
          float2 y = Y[((size_t)d * NF + u) * NV + v];
          Ar = fmaf(y.x, cd, Ar);  Ai = fmaf(y.y, cd, Ai);
          Br = fmaf(y.x, sd, Br);  Bi = fmaf(y.y, sd, Bi);
          Pm = fmaf(cd, cd, Pm);  Qm = fmaf(cd, sd, Qm);  Rm = fmaf(sd, sd, Rm);
          float yk = sqrtf(fmaf(y.x, y.x, y.y * y.y)) * k;
          yktmp[d] = yk;
          S0 = fmaf(yk, yk, S0);
          rot(cd, sd, stc, sts);
        }
#pragma unroll
        for (int jj = 0; jj < ND / 4; ++jj)
          Yk4[(size_t)jj * NPIXP + p] = make_float4(yktmp[2 * jj], yktmp[63 - 2 * jj],
                                                    yktmp[2 * jj + 1], yktmp[62 - 2 * jj]);
        prm[IP_AR * NPIXP + p] = Ar;   prm[IP_AI * NPIXP + p] = Ai;
        prm[IP_BR * NPIXP + p] = Br;   prm[IP_BI * NPIXP + p] = Bi;
        prm[IP_P * NPIXP + p] = Pm;    prm[IP_Q * NPIXP + p] = Qm;
        prm[IP_R * NPIXP + p] = Rm;    prm[IP_C2T * NPIXP + p] = c2t;
        prm[IP_S2T * NPIXP + p] = s2t; prm[IP_K * NPIXP + p] = k;
        prm[IP_CD0 * NPIXP + p] = cd0f; prm[IP_SD0 * NPIXP + p] = sd0f;
        prm[IP_CD1 * NPIXP + p] = cd1s; prm[IP_SD1 * NPIXP + p] = sd1s;
        prm[IP_TCD * NPIXP + p] = tcd; prm[IP_S0 * NPIXP + p] = S0;
        prm[IP_W * NPIXP + p] = w_;
      }
    }
  }
  gbar(grp, root, gen);

  // ---- phase 4: cand — dual Chebyshev chains over virtual blocks ----
  {
    int wid = threadIdx.x >> 6;
    int lane = threadIdx.x & 63;
    __shared__ float sdata[CPB][4];
    for (int vb = blockIdx.x; vb < NXBLK * (NC / CPB); vb += NBLK) {
      int bx = vb % NXBLK;
      int by = vb / NXBLK;
      int p = bx * 256 + threadIdx.x;
      int c0 = by * CPB;
      float Ar = prm[IP_AR * NPIXP + p], Ai = prm[IP_AI * NPIXP + p];
      float Br = prm[IP_BR * NPIXP + p], Bi = prm[IP_BI * NPIXP + p];
      float Pm = prm[IP_P * NPIXP + p], Qm = prm[IP_Q * NPIXP + p], Rm = prm[IP_R * NPIXP + p];
      float c2t = prm[IP_C2T * NPIXP + p], s2t = prm[IP_S2T * NPIXP + p];
      float k = prm[IP_K * NPIXP + p];
      float cd0 = prm[IP_CD0 * NPIXP + p], sd0 = prm[IP_SD0 * NPIXP + p];
      float cd1 = prm[IP_CD1 * NPIXP + p], sd1 = prm[IP_SD1 * NPIXP + p];
      float tcd = prm[IP_TCD * NPIXP + p], S0 = prm[IP_S0 * NPIXP + p];
      float wgt = prm[IP_W * NPIXP + p];
      float4 yk[ND / 4];
#pragma unroll
      for (int jj = 0; jj < ND / 4; ++jj) yk[jj] = Yk4[(size_t)jj * NPIXP + p];
#pragma unroll
      for (int jj = 0; jj < ND / 4; ++jj)
        asm volatile("" : "+v"(yk[jj].x), "+v"(yk[jj].y), "+v"(yk[jj].z), "+v"(yk[jj].w));
      for (int ci = 0; ci < CPB; ++ci) {
        int c = c0 + ci;
        float dc = cand[c * 3 + 0], xx = cand[c * 3 + 1], yy = cand[c * 3 + 2];
        float w_ = fmaf(xx, c2t, fmaf(yy, s2t, dc));
        float kw = k * w_;
        float sw, cw;
        __sincosf(kw, &sw, &cw);
        float rr = fmaf(cw, Ar, sw * Br);
        float ri = fmaf(cw, Ai, sw * Bi);
        float lhs = fmaf(cw * cw, Pm, fmaf(2.f * cw * sw, Qm, sw * sw * Rm));
        float rabs = __builtin_amdgcn_sqrtf(fmaf(rr, rr, ri * ri));
        float rl = __builtin_amdgcn_rcpf(lhs);
        float e = fmaf(-lhs, rl, 1.f);
        rl = fmaf(rl, e, rl);
        float kX = k * rabs * rl;
        float t0 = cd0 * cw, u0 = sd0 * sw;
        float t1 = cd1 * cw, u1 = sd1 * sw;
        float Am1 = t0 + u0, Bm1 = t0 - u0;
        float Ac  = t1 + u1, Bc  = t1 - u1;
        float MA0 = yk[0].x * fabsf(Am1);
        float MB0 = yk[0].y * fabsf(Bm1);
        float MA1 = yk[0].z * fabsf(Ac);
        float MB1 = yk[0].w * fabsf(Bc);
#pragma unroll
        for (int jj = 1; jj < ND / 4; ++jj) {
          float An = fmaf(tcd, Ac, -Am1);
          float Bn = fmaf(tcd, Bc, -Bm1);
          MA0 = fmaf(yk[jj].x, fabsf(An), MA0);
          MB0 = fmaf(yk[jj].y, fabsf(Bn), MB0);
          float An2 = fmaf(tcd, An, -Ac);
          float Bn2 = fmaf(tcd, Bn, -Bc);
          MA1 = fmaf(yk[jj].z, fabsf(An2), MA1);
          MB1 = fmaf(yk[jj].w, fabsf(Bn2), MB1);
          Am1 = An; Ac = An2;
          Bm1 = Bn; Bc = Bn2;
        }
        float M = (MA0 + MA1) + (MB0 + MB1);
        float contrib = fmaf(kX * kX, lhs, fmaf(-2.f * kX, M, S0)) * wgt;
        for (int off = 32; off > 0; off >>= 1) contrib += __shfl_xor(contrib, off);
        if (lane == 0) sdata[ci][wid] = contrib;
      }
      __syncthreads();
      if (threadIdx.x < CPB) {
        int ci = threadIdx.x;
        float s = (sdata[ci][0] + sdata[ci][1]) + (sdata[ci][2] + sdata[ci][3]);
        partial[(size_t)bx * NC + c0 + ci] = s;
      }
      __syncthreads();
    }
  }
  gbar(grp, root, gen);

  // ---- phase 5: argmin (block 0; 2 candidates per thread) ----
  if (blockIdx.x == 0) {
    __shared__ float sl[NTHR];
    __shared__ int si[NTHR];
    int c1 = threadIdx.x, c2 = threadIdx.x + NTHR;
    float s1 = 0.f, s2 = 0.f;
#pragma unroll
    for (int j = 0; j < NJ; ++j) {
      s1 += partial[(size_t)j * NC + c1];
      s2 += partial[(size_t)j * NC + c2];
    }
    float l; int i;
    if (s2 < s1) { l = s2; i = c2; } else { l = s1; i = c1; }
    sl[threadIdx.x] = l; si[threadIdx.x] = i;
    __syncthreads();
    for (int off = 128; off > 0; off >>= 1) {
      if (threadIdx.x < off) {
        float l2 = sl[threadIdx.x + off]; int i2 = si[threadIdx.x + off];
        if (l2 < sl[threadIdx.x] || (l2 == sl[threadIdx.x] && i2 < si[threadIdx.x])) {
          sl[threadIdx.x] = l2; si[threadIdx.x] = i2;
        }
      }
      __syncthreads();
    }
    if (threadIdx.x == 0) {
      int bi = si[0];
      out[6400] = cand[bi * 3 + 0];
      out[6401] = cand[bi * 3 + 1];
      out[6402] = cand[bi * 3 + 2];
      out[6403] = sl[0] * (1.f / 1638400.f);
      *bestIdx = bi;
    }
  }
  gbar(grp, root, gen);

  // ---- phase 6: ifft_u — X row (Hermitian expand) -> LDS -> row DFT -> G ----
  {
    __shared__ float xr[NF], xi[NF];
    if (blockIdx.x < NF) {
      int u = blockIdx.x;
      int bi = *bestIdx;
      float dc = cand[bi * 3 + 0], xx = cand[bi * 3 + 1], yy = cand[bi * 3 + 2];
      int v = threadIdx.x;
      if (v < NF) {
        float sign = 1.f;
        int ph;
        if (v <= 80) {
          ph = u * NV + v;
        } else {
          int u2 = (NF - u) % NF;
          ph = u2 * NV + (NF - v);
          sign = -1.f;
        }
        float Ar = prm[IP_AR * NPIXP + ph], Ai = prm[IP_AI * NPIXP + ph];
        float Br = prm[IP_BR * NPIXP + ph], Bi = prm[IP_BI * NPIXP + ph];
        float Pm = prm[IP_P * NPIXP + ph], Qm = prm[IP_Q * NPIXP + ph], Rm = prm[IP_R * NPIXP + ph];
        float c2t = prm[IP_C2T * NPIXP + ph], s2t = prm[IP_S2T * NPIXP + ph];
        float k = prm[IP_K * NPIXP + ph];
        float w_ = fmaf(xx, c2t, fmaf(yy, s2t, dc));
        float sw, cw;
        sincosf(k * w_, &sw, &cw);
        float rr = fmaf(cw, Ar, sw * Br);
        float ri = fmaf(cw, Ai, sw * Bi);
        float lhs = fmaf(cw * cw, Pm, fmaf(2.f * cw * sw, Qm, sw * sw * Rm));
        xr[v] = rr / lhs;
        xi[v] = sign * ri / lhs;
      }
      __syncthreads();
      int b = threadIdx.x;
      if (b < NP) {
        int xb = (b + 120) % NF;
        float stc, sts;
        sincosf(TWO_PI * (float)xb / (float)NF, &sts, &stc);
        float c = 1.f, s = 0.f, accR = 0.f, accI = 0.f;
#pragma unroll 4
        for (int vv = 0; vv < NF; ++vv) {
          float xrv = xr[vv], xiv = xi[vv];
          accR = fmaf(xrv, c, accR); accR = fmaf(-xiv, s, accR);
          accI = fmaf(xrv, s, accI); accI = fmaf(xiv, c, accI);
          rot(c, s, stc, sts);
        }
        G[(size_t)u * NP + b] = make_float2(accR, accI);
      }
    }
  }
  gbar(grp, root, gen);

  // ---- phase 7: ifft_y — out[a][b] (wave-chunk spread, 100 chunks) ----
  {
    int w = threadIdx.x >> 6;
    int lane = threadIdx.x & 63;
    int cch = blockIdx.x + NBLK * w;
    if (cch < (NP * NP) / 64) {           // 100 chunks
      int idx = cch * 64 + lane;
      int b = idx % NP;
      int a = idx / NP;
      int ya = (a + 120) % NF;
      float stc, sts;
      sincosf(TWO_PI * (float)ya / (float)NF, &sts, &stc);
      float c = 1.f, s = 0.f, accR = 0.f;
#pragma unroll 4
      for (int u = 0; u < NF; ++u) {
        float2 g = G[(size_t)u * NP + b];
        accR = fmaf(g.x, c, accR);
        accR = fmaf(-g.y, s, accR);
        rot(c, s, stc, sts);
      }
      out[idx] = accR * (1.f / 25600.f);
    }
  }
}

extern "C" void kernel_launch(void* const* d_in, const int* in_sizes, int n_in,
                              void* d_out, int out_size, void* d_ws, size_t ws_size,
                              hipStream_t stream) {
  (void)in_sizes; (void)n_in; (void)out_size; (void)ws_size;
  const float* patch  = (const float*)d_in[0];
  const float* gw     = (const float*)d_in[1];
  const float* delays = (const float*)d_in[2];
  const float* theta  = (const float*)d_in[4];
  const float* kloss  = (const float*)d_in[5];
  const float* cand   = (const float*)d_in[6];
  float* out = (float*)d_out;

  char* ws = (char*)d_ws;
  size_t off = 0;
  float2* Y = (float2*)(ws + off);      off += (size_t)ND * NF * NV * 8;     // 6,635,520
  float2* T = (float2*)(ws + off);      off += (size_t)ND * NP * NV * 8;     // 3,317,760
  float4* Yk4 = (float4*)(ws + off);    off += (size_t)(ND / 4) * NPIXP * 16;// 3,342,336
  float* prm = (float*)(ws + off);      off += (size_t)NPRM * NPIXP * 4;     //   887,808
  float* partial = (float*)(ws + off);  off += (size_t)NJ * NC * 4;          //   104,448
  float2* G = (float2*)(ws + off);      off += (size_t)NF * NP * 8;          //   102,400
  int* bestIdx = (int*)(ws + off);      off += 256;
  off = (off + 255) & ~(size_t)255;
  int* bar = (int*)(ws + off);          // 64 group counters (64B apart) + root + gen

  hipMemsetAsync(bar, 0, 8192, stream);
  hipLaunchKernelGGL(k_mega, dim3(NBLK), dim3(NTHR), 0, stream,
                     patch, gw, delays, kloss, theta, cand, out,
                     T, Y, Yk4, prm, partial, G, bestIdx, bar);
}

// Round 7
// 168.070 us; speedup vs baseline: 2.0604x; 1.5043x over previous
//
#include <hip/hip_runtime.h>

#define NF 160
#define NP 80
#define ND 64
#define NC 512
#define NV 81                  // stored v columns 0..80 (Hermitian half)
#define NPIXH (NF*NV)          // 12960
#define NPIXP 13056            // padded to 51*256
#define NXBLK 51
#define NJ NXBLK               // partial rows
#define CPB 32                 // candidates per virtual block
#define NGROUPS (NC/CPB)       // 16 -> 816 virtual blocks
#define NBLK3 512              // K3 grid: 2 blocks/CU guaranteed resident
#define NGRP 64                // barrier groups
#define GSZ (NBLK3/NGRP)       // 8 blocks per group
#define GRP_STRIDE 16          // 64B counter spacing
#define TWO_PI 6.283185307179586f

// prm slots (only what ifft_u needs)
#define JP_AR 0
#define JP_AI 1
#define JP_BR 2
#define JP_BI 3
#define JP_P  4
#define JP_Q  5
#define JP_R  6
#define JP_C2T 7
#define JP_S2T 8
#define JP_K  9
#define NPRM2 10

__device__ __forceinline__ void rot(float& c, float& s, float stc, float sts) {
  float t1 = s * sts;
  float t2 = s * stc;
  float cn = fmaf(c, stc, -t1);
  s = fmaf(c, sts, t2);
  c = cn;
}

__device__ __forceinline__ void start_i_pow(int n, float& c, float& s) {
  switch (n & 3) {
    case 0: c = 1.f; s = 0.f; break;
    case 1: c = 0.f; s = 1.f; break;
    case 2: c = -1.f; s = 0.f; break;
    default: c = 0.f; s = -1.f; break;
  }
}

// ---- relaxed agent-scope atomic payload helpers (L2-bypass, no fences) ----
__device__ __forceinline__ float at_load_f(const float* p) {
  unsigned u = __hip_atomic_load((const unsigned*)p, __ATOMIC_RELAXED, __HIP_MEMORY_SCOPE_AGENT);
  return __uint_as_float(u);
}
__device__ __forceinline__ void at_store_f(float* p, float v) {
  __hip_atomic_store((unsigned*)p, __float_as_uint(v), __ATOMIC_RELAXED, __HIP_MEMORY_SCOPE_AGENT);
}
__device__ __forceinline__ float2 at_load_f2(const float2* p) {
  unsigned long long u = __hip_atomic_load((const unsigned long long*)p, __ATOMIC_RELAXED, __HIP_MEMORY_SCOPE_AGENT);
  float2 v;
  v.x = __uint_as_float((unsigned)u);
  v.y = __uint_as_float((unsigned)(u >> 32));
  return v;
}
__device__ __forceinline__ void at_store_f2(float2* p, float2 v) {
  unsigned long long u = ((unsigned long long)__float_as_uint(v.y) << 32) | __float_as_uint(v.x);
  __hip_atomic_store((unsigned long long*)p, u, __ATOMIC_RELAXED, __HIP_MEMORY_SCOPE_AGENT);
}

// Fence-free grid barrier: monotonic two-level counters, relaxed agent atomics.
// __syncthreads drains each wave's vmcnt (atomic stores at coherence point)
// before lane 0 announces arrival; no cache-wide fences anywhere.
__device__ __forceinline__ void gbar(int* bar) {
  __syncthreads();
  if (threadIdx.x == 0) {
    int* gc = bar + (blockIdx.x & (NGRP - 1)) * GRP_STRIDE;
    int* root = bar + NGRP * GRP_STRIDE;
    int* gen = root + 16;
    asm volatile("s_waitcnt vmcnt(0)" ::: "memory");
    int g0 = __hip_atomic_load(gen, __ATOMIC_RELAXED, __HIP_MEMORY_SCOPE_AGENT);
    int a = __hip_atomic_fetch_add(gc, 1, __ATOMIC_RELAXED, __HIP_MEMORY_SCOPE_AGENT);
    if ((a & (GSZ - 1)) == (GSZ - 1)) {
      int r = __hip_atomic_fetch_add(root, 1, __ATOMIC_RELAXED, __HIP_MEMORY_SCOPE_AGENT);
      if ((r & (NGRP - 1)) == (NGRP - 1))
        __hip_atomic_fetch_add(gen, 1, __ATOMIC_RELAXED, __HIP_MEMORY_SCOPE_AGENT);
    }
    while (__hip_atomic_load(gen, __ATOMIC_RELAXED, __HIP_MEMORY_SCOPE_AGENT) == g0)
      __builtin_amdgcn_s_sleep(4);
    asm volatile("" ::: "memory");
  }
  __syncthreads();
}

// K1: T[d][a][v] = sum_b yw[d,a,b] * e^{-2pi i v (b-40)/160}, v in 0..80
__global__ __launch_bounds__(256) void k_fft_x(const float* __restrict__ patch,
                                               const float* __restrict__ gw,
                                               float2* __restrict__ T) {
  int idx = blockIdx.x * 256 + threadIdx.x;   // 414720
  int v = idx % NV;
  int a = (idx / NV) % NP;
  int d = idx / (NV * NP);
  float c, s;
  start_i_pow(v, c, s);
  float stc, sts;
  sincosf(-TWO_PI * (float)v / (float)NF, &sts, &stc);
  const float* prow = patch + (size_t)(d * NP + a) * NP;
  const float* grow = gw + a * NP;
  float accR = 0.f, accI = 0.f;
#pragma unroll 4
  for (int b = 0; b < NP; ++b) {
    float f = prow[b] * grow[b];
    accR = fmaf(f, c, accR);
    accI = fmaf(f, s, accI);
    rot(c, s, stc, sts);
  }
  T[idx] = make_float2(accR, accI);
}

// K2: Y[d][u*NV+v] = sum_a T[d][a][v] * e^{-2pi i u (a-40)/160}
__global__ __launch_bounds__(256) void k_fft_y(const float2* __restrict__ T,
                                               float2* __restrict__ Y) {
  int idx = blockIdx.x * 256 + threadIdx.x;   // 207360
  int v = idx % NV;
  int ug = (idx / NV) % 40;
  int d = idx / (NV * 40);
  float c[4], s[4], aR[4], aI[4], stc[4], sts[4];
#pragma unroll
  for (int j = 0; j < 4; ++j) {
    int u = ug * 4 + j;
    start_i_pow(u, c[j], s[j]);
    sincosf(-TWO_PI * (float)u / (float)NF, &sts[j], &stc[j]);
    aR[j] = 0.f; aI[j] = 0.f;
  }
  const float2* Tb = T + (size_t)(d * NP) * NV + v;
#pragma unroll 4
  for (int a = 0; a < NP; ++a) {
    float2 t = Tb[(size_t)a * NV];
#pragma unroll
    for (int j = 0; j < 4; ++j) {
      aR[j] = fmaf(t.x, c[j], aR[j]);
      aR[j] = fmaf(-t.y, s[j], aR[j]);
      aI[j] = fmaf(t.x, s[j], aI[j]);
      aI[j] = fmaf(t.y, c[j], aI[j]);
      rot(c[j], s[j], stc[j], sts[j]);
    }
  }
#pragma unroll
  for (int j = 0; j < 4; ++j) {
    int u = ug * 4 + j;
    Y[(size_t)d * NPIXH + u * NV + v] = make_float2(aR[j], aI[j]);
  }
}

// K3: fused tail: [prep+cand] -> gbar -> [argmin+ifft_u] -> gbar -> [ifft_y]
__global__ __launch_bounds__(256, 2) void k_tail(
    const float2* __restrict__ Y, const float* __restrict__ delays,
    const float* __restrict__ kloss, const float* __restrict__ theta,
    const float* __restrict__ cand, float* __restrict__ out,
    float* __restrict__ prm, float* __restrict__ partial,
    float2* __restrict__ G, int* __restrict__ bar) {
  __shared__ __align__(16) char pool[51456];

  // ---- phase A: prep (per-block, from Y) + 32-candidate scan ----
  {
    float (*sdata)[4] = (float (*)[4])pool;
    int wid = threadIdx.x >> 6;
    int lane = threadIdx.x & 63;
    for (int vb = blockIdx.x; vb < NXBLK * NGROUPS; vb += NBLK3) {
      int bx = vb % NXBLK;
      int by = vb / NXBLK;
      int p = bx * 256 + threadIdx.x;
      int c0 = by * CPB;
      float yk64[ND];
      float Ar, Ai, Br, Bi, Pm, Qm, Rm, S0, c2t, s2t, k, cd0, sd0, cd1s, sd1s, tcd, wgt;
      if (p < NPIXH) {
        int u = p / NV, v = p % NV;
        k = kloss[u * NF + v];
        float th = theta[((u + 80) % NF) * NF + ((v + 80) % NF)];
        c2t = cosf(2.f * th); s2t = sinf(2.f * th);
        if (v == 0 || v == 80) {
          if (u == 0 || u == 80) wgt = 1.f;
          else if (u < 80) wgt = 2.f;
          else wgt = 0.f;
        } else wgt = 2.f;
        float d0 = delays[0], d1 = delays[1];
        sincosf(k * d0, &sd0, &cd0);
        float stc, sts;
        sincosf(k * (d1 - d0), &sts, &stc);
        tcd = 2.f * stc;
        float cd = cd0, sd = sd0;
        cd1s = 0.f; sd1s = 0.f;
        Ar = Ai = Br = Bi = Pm = Qm = Rm = S0 = 0.f;
#pragma unroll
        for (int d = 0; d < ND; ++d) {
          if (d == 1) { cd1s = cd; sd1s = sd; }
          float2 y = Y[(size_t)d * NPIXH + p];
          Ar = fmaf(y.x, cd, Ar);  Ai = fmaf(y.y, cd, Ai);
          Br = fmaf(y.x, sd, Br);  Bi = fmaf(y.y, sd, Bi);
          Pm = fmaf(cd, cd, Pm);  Qm = fmaf(cd, sd, Qm);  Rm = fmaf(sd, sd, Rm);
          float yk = sqrtf(fmaf(y.x, y.x, y.y * y.y)) * k;
          yk64[d] = yk;
          S0 = fmaf(yk, yk, S0);
          rot(cd, sd, stc, sts);
        }
      } else {
        // padding lane: inert values, zero weight
#pragma unroll
        for (int d = 0; d < ND; ++d) yk64[d] = 0.f;
        Ar = Ai = Br = Bi = 0.f; Pm = 1.f; Qm = 0.f; Rm = 1.f; S0 = 0.f;
        c2t = s2t = 0.f; k = 0.f; cd0 = 1.f; sd0 = 0.f; cd1s = 1.f; sd1s = 0.f;
        tcd = 2.f; wgt = 0.f;
      }
#pragma unroll
      for (int jj = 0; jj < ND; jj += 4)
        asm volatile("" : "+v"(yk64[jj]), "+v"(yk64[jj + 1]),
                          "+v"(yk64[jj + 2]), "+v"(yk64[jj + 3]));
      if (by == 0 && p < NPIXH) {   // publish solve params for ifft_u (atomic)
        at_store_f(&prm[JP_AR * NPIXP + p], Ar);
        at_store_f(&prm[JP_AI * NPIXP + p], Ai);
        at_store_f(&prm[JP_BR * NPIXP + p], Br);
        at_store_f(&prm[JP_BI * NPIXP + p], Bi);
        at_store_f(&prm[JP_P * NPIXP + p], Pm);
        at_store_f(&prm[JP_Q * NPIXP + p], Qm);
        at_store_f(&prm[JP_R * NPIXP + p], Rm);
        at_store_f(&prm[JP_C2T * NPIXP + p], c2t);
        at_store_f(&prm[JP_S2T * NPIXP + p], s2t);
        at_store_f(&prm[JP_K * NPIXP + p], k);
      }
      for (int ci = 0; ci < CPB; ++ci) {
        int c = c0 + ci;
        float dc = cand[c * 3 + 0], xx = cand[c * 3 + 1], yy = cand[c * 3 + 2];
        float w_ = fmaf(xx, c2t, fmaf(yy, s2t, dc));
        float kw = k * w_;
        float sw, cw;
        __sincosf(kw, &sw, &cw);
        float rr = fmaf(cw, Ar, sw * Br);
        float ri = fmaf(cw, Ai, sw * Bi);
        float lhs = fmaf(cw * cw, Pm, fmaf(2.f * cw * sw, Qm, sw * sw * Rm));
        float rabs = __builtin_amdgcn_sqrtf(fmaf(rr, rr, ri * ri));
        float rl = __builtin_amdgcn_rcpf(lhs);
        float e = fmaf(-lhs, rl, 1.f);
        rl = fmaf(rl, e, rl);
        float kX = k * rabs * rl;
        float t0 = cd0 * cw, u0 = sd0 * sw;
        float t1 = cd1s * cw, u1 = sd1s * sw;
        float Am1 = t0 + u0, Bm1 = t0 - u0;
        float Ac = t1 + u1, Bc = t1 - u1;
        float MA0 = yk64[0] * fabsf(Am1);
        float MB0 = yk64[63] * fabsf(Bm1);
        float MA1 = yk64[1] * fabsf(Ac);
        float MB1 = yk64[62] * fabsf(Bc);
#pragma unroll
        for (int jj = 1; jj < ND / 4; ++jj) {
          float An = fmaf(tcd, Ac, -Am1);
          float Bn = fmaf(tcd, Bc, -Bm1);
          MA0 = fmaf(yk64[2 * jj], fabsf(An), MA0);
          MB0 = fmaf(yk64[63 - 2 * jj], fabsf(Bn), MB0);
          float An2 = fmaf(tcd, An, -Ac);
          float Bn2 = fmaf(tcd, Bn, -Bc);
          MA1 = fmaf(yk64[2 * jj + 1], fabsf(An2), MA1);
          MB1 = fmaf(yk64[62 - 2 * jj], fabsf(Bn2), MB1);
          Am1 = An; Ac = An2; Bm1 = Bn; Bc = Bn2;
        }
        float M = (MA0 + MA1) + (MB0 + MB1);
        float contrib = fmaf(kX * kX, lhs, fmaf(-2.f * kX, M, S0)) * wgt;
        for (int off = 32; off > 0; off >>= 1) contrib += __shfl_xor(contrib, off);
        if (lane == 0) sdata[ci][wid] = contrib;
      }
      __syncthreads();
      if (threadIdx.x < CPB) {
        int ci = threadIdx.x;
        float s = (sdata[ci][0] + sdata[ci][1]) + (sdata[ci][2] + sdata[ci][3]);
        at_store_f(&partial[(size_t)bx * NC + c0 + ci], s);
      }
      __syncthreads();
    }
  }
  gbar(bar);

  // ---- phase B: redundant argmin + ifft_u (blocks 0..159) ----
  if (blockIdx.x < NF) {
    float* sl = (float*)pool;                 // 1KB
    int* si = (int*)(pool + 1024);            // 1KB
    float* xr = (float*)(pool + 2048);        // 640B
    float* xi = (float*)(pool + 2688);        // 640B
    int c1 = threadIdx.x, c2 = threadIdx.x + 256;
    float s1 = 0.f, s2 = 0.f;
#pragma unroll
    for (int j = 0; j < NJ; ++j) {
      s1 += at_load_f(&partial[(size_t)j * NC + c1]);
      s2 += at_load_f(&partial[(size_t)j * NC + c2]);
    }
    float l; int i;
    if (s2 < s1) { l = s2; i = c2; } else { l = s1; i = c1; }
    sl[threadIdx.x] = l; si[threadIdx.x] = i;
    __syncthreads();
    for (int off = 128; off > 0; off >>= 1) {
      if (threadIdx.x < off) {
        float l2 = sl[threadIdx.x + off]; int i2 = si[threadIdx.x + off];
        if (l2 < sl[threadIdx.x] || (l2 == sl[threadIdx.x] && i2 < si[threadIdx.x])) {
          sl[threadIdx.x] = l2; si[threadIdx.x] = i2;
        }
      }
      __syncthreads();
    }
    int bi = si[0];
    if (blockIdx.x == 0 && threadIdx.x == 0) {
      out[6400] = cand[bi * 3 + 0];
      out[6401] = cand[bi * 3 + 1];
      out[6402] = cand[bi * 3 + 2];
      out[6403] = sl[0] * (1.f / 1638400.f);
    }
    int u = blockIdx.x;
    float dc = cand[bi * 3 + 0], xx = cand[bi * 3 + 1], yy = cand[bi * 3 + 2];
    int v = threadIdx.x;
    if (v < NF) {
      float sign = 1.f;
      int ph;
      if (v <= 80) {
        ph = u * NV + v;
      } else {
        int u2 = (NF - u) % NF;
        ph = u2 * NV + (NF - v);
        sign = -1.f;
      }
      float Ar = at_load_f(&prm[JP_AR * NPIXP + ph]);
      float Ai = at_load_f(&prm[JP_AI * NPIXP + ph]);
      float Br = at_load_f(&prm[JP_BR * NPIXP + ph]);
      float Bi = at_load_f(&prm[JP_BI * NPIXP + ph]);
      float Pm = at_load_f(&prm[JP_P * NPIXP + ph]);
      float Qm = at_load_f(&prm[JP_Q * NPIXP + ph]);
      float Rm = at_load_f(&prm[JP_R * NPIXP + ph]);
      float c2t = at_load_f(&prm[JP_C2T * NPIXP + ph]);
      float s2t = at_load_f(&prm[JP_S2T * NPIXP + ph]);
      float k = at_load_f(&prm[JP_K * NPIXP + ph]);
      float w_ = fmaf(xx, c2t, fmaf(yy, s2t, dc));
      float sw, cw;
      sincosf(k * w_, &sw, &cw);
      float rr = fmaf(cw, Ar, sw * Br);
      float ri = fmaf(cw, Ai, sw * Bi);
      float lhs = fmaf(cw * cw, Pm, fmaf(2.f * cw * sw, Qm, sw * sw * Rm));
      xr[v] = rr / lhs;
      xi[v] = sign * ri / lhs;
    }
    __syncthreads();
    int b = threadIdx.x;
    if (b < NP) {
      int xb = (b + 120) % NF;
      float stc, sts;
      sincosf(TWO_PI * (float)xb / (float)NF, &sts, &stc);
      float c = 1.f, s = 0.f, accR = 0.f, accI = 0.f;
#pragma unroll 4
      for (int vv = 0; vv < NF; ++vv) {
        float xrv = xr[vv], xiv = xi[vv];
        accR = fmaf(xrv, c, accR); accR = fmaf(-xiv, s, accR);
        accI = fmaf(xrv, s, accI); accI = fmaf(xiv, c, accI);
        rot(c, s, stc, sts);
      }
      at_store_f2(&G[(size_t)u * NP + b], make_float2(accR, accI));
    }
  }
  gbar(bar);

  // ---- phase C: ifft_y via two-half LDS staging (blocks 0..24) ----
  if (blockIdx.x < 25) {
    float2* Gl = (float2*)pool;               // 80*80 float2 = 51.2KB per half
    int idx = blockIdx.x * 256 + threadIdx.x; // 6400 items
    int b = idx % NP;
    int a = idx / NP;
    int ya = (a + 120) % NF;
    float stc, sts;
    sincosf(TWO_PI * (float)ya / (float)NF, &sts, &stc);
    float c = 1.f, s = 0.f, accR = 0.f;
    for (int h = 0; h < 2; ++h) {
      __syncthreads();
#pragma unroll
      for (int j = 0; j < 25; ++j)
        Gl[threadIdx.x + j * 256] = at_load_f2(&G[h * 6400 + threadIdx.x + j * 256]);
      __syncthreads();
#pragma unroll 4
      for (int uu = 0; uu < 80; ++uu) {
        float2 g = Gl[uu * NP + b];
        accR = fmaf(g.x, c, accR);
        accR = fmaf(-g.y, s, accR);
        rot(c, s, stc, sts);
      }
    }
    out[idx] = accR * (1.f / 25600.f);
  }
}

extern "C" void kernel_launch(void* const* d_in, const int* in_sizes, int n_in,
                              void* d_out, int out_size, void* d_ws, size_t ws_size,
                              hipStream_t stream) {
  (void)in_sizes; (void)n_in; (void)out_size; (void)ws_size;
  const float* patch  = (const float*)d_in[0];
  const float* gw     = (const float*)d_in[1];
  const float* delays = (const float*)d_in[2];
  const float* theta  = (const float*)d_in[4];
  const float* kloss  = (const float*)d_in[5];
  const float* cand   = (const float*)d_in[6];
  float* out = (float*)d_out;

  char* ws = (char*)d_ws;
  size_t off = 0;
  float2* Y = (float2*)(ws + off);      off += (size_t)ND * NPIXH * 8;       // 6,635,520
  float2* T = (float2*)(ws + off);      off += (size_t)ND * NP * NV * 8;     // 3,317,760
  float* prm = (float*)(ws + off);      off += (size_t)NPRM2 * NPIXP * 4;    //   522,240
  float* partial = (float*)(ws + off);  off += (size_t)NJ * NC * 4;          //   104,448
  float2* G = (float2*)(ws + off);      off += (size_t)NF * NP * 8;          //   102,400
  off = (off + 255) & ~(size_t)255;
  int* bar = (int*)(ws + off);          // 64 spaced group counters + root + gen

  hipMemsetAsync(bar, 0, 8192, stream);
  hipLaunchKernelGGL(k_fft_x, dim3((ND * NP * NV) / 256), dim3(256), 0, stream,
                     patch, gw, T);
  hipLaunchKernelGGL(k_fft_y, dim3((ND * 40 * NV) / 256), dim3(256), 0, stream,
                     T, Y);
  hipLaunchKernelGGL(k_tail, dim3(NBLK3), dim3(256), 0, stream,
                     Y, delays, kloss, theta, cand, out, prm, partial, G, bar);
}

// Round 8
// 103.185 us; speedup vs baseline: 3.3560x; 1.6288x over previous
//
#include <hip/hip_runtime.h>

#define NF 160
#define NP 80
#define ND 64
#define NC 512
#define NV 81                  // stored v columns 0..80 (Hermitian half)
#define NPIXH (NF*NV)          // 12960
#define NPIXP 13056            // padded to 51*256
#define NXBLK 51
#define NJ NXBLK               // partial rows (reduced in-block)
#define CPB 16                 // candidates per block
#define TWO_PI 6.283185307179586f

// per-pixel precomputed parameter slots
#define IP_AR 0
#define IP_AI 1
#define IP_BR 2
#define IP_BI 3
#define IP_P  4
#define IP_Q  5
#define IP_R  6
#define IP_C2T 7
#define IP_S2T 8
#define IP_K  9
#define IP_CD0 10
#define IP_SD0 11
#define IP_CD1 12
#define IP_SD1 13
#define IP_TCD 14
#define IP_S0 15
#define IP_W  16
#define NPRM 17

__device__ __forceinline__ void rot(float& c, float& s, float stc, float sts) {
  float t1 = s * sts;
  float t2 = s * stc;
  float cn = fmaf(c, stc, -t1);
  s = fmaf(c, sts, t2);
  c = cn;
}

__device__ __forceinline__ void start_i_pow(int n, float& c, float& s) {
  switch (n & 3) {
    case 0: c = 1.f; s = 0.f; break;
    case 1: c = 0.f; s = 1.f; break;
    case 2: c = -1.f; s = 0.f; break;
    default: c = 0.f; s = -1.f; break;
  }
}

// K1: T[d][a][v] = sum_b yw[d,a,b] * e^{-2pi i v (b-40)/160}, v in 0..80
__global__ __launch_bounds__(256) void k_fft_x(const float* __restrict__ patch,
                                               const float* __restrict__ gw,
                                               float2* __restrict__ T) {
  int idx = blockIdx.x * 256 + threadIdx.x;   // ND*NP*NV = 414720
  int v = idx % NV;
  int a = (idx / NV) % NP;
  int d = idx / (NV * NP);
  float c, s;
  start_i_pow(v, c, s);
  float stc, sts;
  sincosf(-TWO_PI * (float)v / (float)NF, &sts, &stc);
  const float* prow = patch + (size_t)(d * NP + a) * NP;
  const float* grow = gw + a * NP;
  float accR = 0.f, accI = 0.f;
#pragma unroll 4
  for (int b = 0; b < NP; ++b) {
    float f = prow[b] * grow[b];
    accR = fmaf(f, c, accR);
    accI = fmaf(f, s, accI);
    rot(c, s, stc, sts);
  }
  T[idx] = make_float2(accR, accI);
}

// K2: Y[d][u][v] = sum_a T[d][a][v] * e^{-2pi i u (a-40)/160}
__global__ __launch_bounds__(256) void k_fft_y(const float2* __restrict__ T,
                                               float2* __restrict__ Y) {
  int idx = blockIdx.x * 256 + threadIdx.x;   // 64*40*81 = 207360
  int v = idx % NV;
  int ug = (idx / NV) % 40;
  int d = idx / (NV * 40);
  float c[4], s[4], aR[4], aI[4], stc[4], sts[4];
#pragma unroll
  for (int j = 0; j < 4; ++j) {
    int u = ug * 4 + j;
    start_i_pow(u, c[j], s[j]);
    sincosf(-TWO_PI * (float)u / (float)NF, &sts[j], &stc[j]);
    aR[j] = 0.f; aI[j] = 0.f;
  }
  const float2* Tb = T + (size_t)(d * NP) * NV + v;
#pragma unroll 4
  for (int a = 0; a < NP; ++a) {
    float2 t = Tb[(size_t)a * NV];
#pragma unroll
    for (int j = 0; j < 4; ++j) {
      aR[j] = fmaf(t.x, c[j], aR[j]);
      aR[j] = fmaf(-t.y, s[j], aR[j]);
      aI[j] = fmaf(t.x, s[j], aI[j]);
      aI[j] = fmaf(t.y, c[j], aI[j]);
      rot(c[j], s[j], stc[j], sts[j]);
    }
  }
#pragma unroll
  for (int j = 0; j < 4; ++j) {
    int u = ug * 4 + j;
    Y[((size_t)d * NF + u) * NV + v] = make_float2(aR[j], aI[j]);
  }
}

// K3: per-pixel candidate-independent moments; Yk4 packing for dual chains
__global__ __launch_bounds__(256) void k_prep(const float2* __restrict__ Y,
                                              const float* __restrict__ delays,
                                              const float* __restrict__ kloss,
                                              const float* __restrict__ theta,
                                              float4* __restrict__ Yk4,
                                              float* __restrict__ prm) {
  int p = blockIdx.x * 256 + threadIdx.x;     // 51*256 = 13056
  if (p >= NPIXH) {
#pragma unroll
    for (int jj = 0; jj < ND / 4; ++jj)
      Yk4[(size_t)jj * NPIXP + p] = make_float4(0.f, 0.f, 0.f, 0.f);
    prm[IP_AR * NPIXP + p] = 0.f;  prm[IP_AI * NPIXP + p] = 0.f;
    prm[IP_BR * NPIXP + p] = 0.f;  prm[IP_BI * NPIXP + p] = 0.f;
    prm[IP_P * NPIXP + p] = 1.f;   prm[IP_Q * NPIXP + p] = 0.f;
    prm[IP_R * NPIXP + p] = 1.f;   prm[IP_C2T * NPIXP + p] = 0.f;
    prm[IP_S2T * NPIXP + p] = 0.f; prm[IP_K * NPIXP + p] = 0.f;
    prm[IP_CD0 * NPIXP + p] = 1.f; prm[IP_SD0 * NPIXP + p] = 0.f;
    prm[IP_CD1 * NPIXP + p] = 1.f; prm[IP_SD1 * NPIXP + p] = 0.f;
    prm[IP_TCD * NPIXP + p] = 2.f; prm[IP_S0 * NPIXP + p] = 0.f;
    prm[IP_W * NPIXP + p] = 0.f;
    return;
  }
  int u = p / NV, v = p % NV;
  float k = kloss[u * NF + v];
  float th = theta[((u + 80) % NF) * NF + ((v + 80) % NF)];
  float c2t = cosf(2.f * th), s2t = sinf(2.f * th);
  float w;
  if (v == 0 || v == 80) {
    if (u == 0 || u == 80) w = 1.f;
    else if (u < 80) w = 2.f;
    else w = 0.f;
  } else w = 2.f;
  float d0 = delays[0], d1 = delays[1];
  float sd0f, cd0f;
  sincosf(k * d0, &sd0f, &cd0f);
  float stc, sts;
  sincosf(k * (d1 - d0), &sts, &stc);
  float tcd = 2.f * stc;
  float cd = cd0f, sd = sd0f;
  float cd1s = 0.f, sd1s = 0.f;
  float Ar = 0.f, Ai = 0.f, Br = 0.f, Bi = 0.f, Pm = 0.f, Qm = 0.f, Rm = 0.f, S0 = 0.f;
  float yktmp[ND];
#pragma unroll
  for (int d = 0; d < ND; ++d) {
    if (d == 1) { cd1s = cd; sd1s = sd; }
    float2 y = Y[((size_t)d * NF + u) * NV + v];
    Ar = fmaf(y.x, cd, Ar);  Ai = fmaf(y.y, cd, Ai);
    Br = fmaf(y.x, sd, Br);  Bi = fmaf(y.y, sd, Bi);
    Pm = fmaf(cd, cd, Pm);  Qm = fmaf(cd, sd, Qm);  Rm = fmaf(sd, sd, Rm);
    float yk = sqrtf(fmaf(y.x, y.x, y.y * y.y)) * k;
    yktmp[d] = yk;
    S0 = fmaf(yk, yk, S0);
    rot(cd, sd, stc, sts);
  }
#pragma unroll
  for (int jj = 0; jj < ND / 4; ++jj)
    Yk4[(size_t)jj * NPIXP + p] = make_float4(yktmp[2 * jj], yktmp[63 - 2 * jj],
                                              yktmp[2 * jj + 1], yktmp[62 - 2 * jj]);
  prm[IP_AR * NPIXP + p] = Ar;   prm[IP_AI * NPIXP + p] = Ai;
  prm[IP_BR * NPIXP + p] = Br;   prm[IP_BI * NPIXP + p] = Bi;
  prm[IP_P * NPIXP + p] = Pm;    prm[IP_Q * NPIXP + p] = Qm;
  prm[IP_R * NPIXP + p] = Rm;    prm[IP_C2T * NPIXP + p] = c2t;
  prm[IP_S2T * NPIXP + p] = s2t; prm[IP_K * NPIXP + p] = k;
  prm[IP_CD0 * NPIXP + p] = cd0f; prm[IP_SD0 * NPIXP + p] = sd0f;
  prm[IP_CD1 * NPIXP + p] = cd1s; prm[IP_SD1 * NPIXP + p] = sd1s;
  prm[IP_TCD * NPIXP + p] = tcd; prm[IP_S0 * NPIXP + p] = S0;
  prm[IP_W * NPIXP + p] = w;
}

// K4: hot kernel — per (pixel, candidate) loss via dual Chebyshev chains.
// yk pinned in VGPRs via opaque asm (prevents compiler sinking loads into loop).
__global__ __launch_bounds__(256, 3) void k_cand(const float4* __restrict__ Yk4,
                                                 const float* __restrict__ prm,
                                                 const float* __restrict__ cand,
                                                 float* __restrict__ partial) {
  int p = blockIdx.x * 256 + threadIdx.x;     // NXBLK=51 blocks in x
  int c0 = blockIdx.y * CPB;
  float Ar = prm[IP_AR * NPIXP + p], Ai = prm[IP_AI * NPIXP + p];
  float Br = prm[IP_BR * NPIXP + p], Bi = prm[IP_BI * NPIXP + p];
  float Pm = prm[IP_P * NPIXP + p], Qm = prm[IP_Q * NPIXP + p], Rm = prm[IP_R * NPIXP + p];
  float c2t = prm[IP_C2T * NPIXP + p], s2t = prm[IP_S2T * NPIXP + p];
  float k = prm[IP_K * NPIXP + p];
  float cd0 = prm[IP_CD0 * NPIXP + p], sd0 = prm[IP_SD0 * NPIXP + p];
  float cd1 = prm[IP_CD1 * NPIXP + p], sd1 = prm[IP_SD1 * NPIXP + p];
  float tcd = prm[IP_TCD * NPIXP + p], S0 = prm[IP_S0 * NPIXP + p];
  float wgt = prm[IP_W * NPIXP + p];
  float4 yk[ND / 4];
#pragma unroll
  for (int jj = 0; jj < ND / 4; ++jj) yk[jj] = Yk4[(size_t)jj * NPIXP + p];
#pragma unroll
  for (int jj = 0; jj < ND / 4; ++jj)
    asm volatile("" : "+v"(yk[jj].x), "+v"(yk[jj].y), "+v"(yk[jj].z), "+v"(yk[jj].w));
  int wid = threadIdx.x >> 6;
  int lane = threadIdx.x & 63;
  __shared__ float sdata[CPB][4];
  for (int ci = 0; ci < CPB; ++ci) {
    int c = c0 + ci;
    float dc = cand[c * 3 + 0], xx = cand[c * 3 + 1], yy = cand[c * 3 + 2];
    float w_ = fmaf(xx, c2t, fmaf(yy, s2t, dc));
    float kw = k * w_;
    float sw, cw;
    __sincosf(kw, &sw, &cw);
    float rr = fmaf(cw, Ar, sw * Br);
    float ri = fmaf(cw, Ai, sw * Bi);
    float lhs = fmaf(cw * cw, Pm, fmaf(2.f * cw * sw, Qm, sw * sw * Rm));
    float rabs = __builtin_amdgcn_sqrtf(fmaf(rr, rr, ri * ri));
    float rl = __builtin_amdgcn_rcpf(lhs);
    float e = fmaf(-lhs, rl, 1.f);
    rl = fmaf(rl, e, rl);                     // refined 1/lhs
    float kX = k * rabs * rl;
    float t0 = cd0 * cw, u0 = sd0 * sw;
    float t1 = cd1 * cw, u1 = sd1 * sw;
    float Am1 = t0 + u0, Bm1 = t0 - u0;       // A_0, B_0
    float Ac  = t1 + u1, Bc  = t1 - u1;       // A_1, B_1
    float MA0 = yk[0].x * fabsf(Am1);
    float MB0 = yk[0].y * fabsf(Bm1);
    float MA1 = yk[0].z * fabsf(Ac);
    float MB1 = yk[0].w * fabsf(Bc);
#pragma unroll
    for (int jj = 1; jj < ND / 4; ++jj) {
      float An = fmaf(tcd, Ac, -Am1);
      float Bn = fmaf(tcd, Bc, -Bm1);
      MA0 = fmaf(yk[jj].x, fabsf(An), MA0);
      MB0 = fmaf(yk[jj].y, fabsf(Bn), MB0);
      float An2 = fmaf(tcd, An, -Ac);
      float Bn2 = fmaf(tcd, Bn, -Bc);
      MA1 = fmaf(yk[jj].z, fabsf(An2), MA1);
      MB1 = fmaf(yk[jj].w, fabsf(Bn2), MB1);
      Am1 = An; Ac = An2;
      Bm1 = Bn; Bc = Bn2;
    }
    float M = (MA0 + MA1) + (MB0 + MB1);
    float contrib = fmaf(kX * kX, lhs, fmaf(-2.f * kX, M, S0)) * wgt;
    for (int off = 32; off > 0; off >>= 1) contrib += __shfl_xor(contrib, off);
    if (lane == 0) sdata[ci][wid] = contrib;
  }
  __syncthreads();
  if (threadIdx.x < CPB) {
    int ci = threadIdx.x;
    float s = (sdata[ci][0] + sdata[ci][1]) + (sdata[ci][2] + sdata[ci][3]);
    partial[(size_t)blockIdx.x * NC + c0 + ci] = s;
  }
}

// K5: fused redundant argmin (per block) + ifft_u row DFT (blocks 0..159)
__global__ __launch_bounds__(256) void k_amin_ifftu(const float* __restrict__ partial,
                                                    const float* __restrict__ prm,
                                                    const float* __restrict__ cand,
                                                    float* __restrict__ out,
                                                    float2* __restrict__ G) {
  __shared__ float sl[256];
  __shared__ int si[256];
  __shared__ float xr[NF], xi[NF];
  int c1 = threadIdx.x, c2 = threadIdx.x + 256;
  float s1 = 0.f, s2 = 0.f;
#pragma unroll
  for (int j = 0; j < NJ; ++j) {
    s1 += partial[(size_t)j * NC + c1];
    s2 += partial[(size_t)j * NC + c2];
  }
  float l; int i;
  if (s2 < s1) { l = s2; i = c2; } else { l = s1; i = c1; }
  sl[threadIdx.x] = l; si[threadIdx.x] = i;
  __syncthreads();
  for (int off = 128; off > 0; off >>= 1) {
    if (threadIdx.x < off) {
      float l2 = sl[threadIdx.x + off]; int i2 = si[threadIdx.x + off];
      if (l2 < sl[threadIdx.x] || (l2 == sl[threadIdx.x] && i2 < si[threadIdx.x])) {
        sl[threadIdx.x] = l2; si[threadIdx.x] = i2;
      }
    }
    __syncthreads();
  }
  int bi = si[0];
  if (blockIdx.x == 0 && threadIdx.x == 0) {
    out[6400] = cand[bi * 3 + 0];
    out[6401] = cand[bi * 3 + 1];
    out[6402] = cand[bi * 3 + 2];
    out[6403] = sl[0] * (1.f / 1638400.f);
  }
  int u = blockIdx.x;
  float dc = cand[bi * 3 + 0], xx = cand[bi * 3 + 1], yy = cand[bi * 3 + 2];
  int v = threadIdx.x;
  if (v < NF) {
    float sign = 1.f;
    int ph;
    if (v <= 80) {
      ph = u * NV + v;
    } else {
      int u2 = (NF - u) % NF;
      ph = u2 * NV + (NF - v);
      sign = -1.f;
    }
    float Ar = prm[IP_AR * NPIXP + ph], Ai = prm[IP_AI * NPIXP + ph];
    float Br = prm[IP_BR * NPIXP + ph], Bi = prm[IP_BI * NPIXP + ph];
    float Pm = prm[IP_P * NPIXP + ph], Qm = prm[IP_Q * NPIXP + ph], Rm = prm[IP_R * NPIXP + ph];
    float c2t = prm[IP_C2T * NPIXP + ph], s2t = prm[IP_S2T * NPIXP + ph];
    float k = prm[IP_K * NPIXP + ph];
    float w_ = fmaf(xx, c2t, fmaf(yy, s2t, dc));
    float sw, cw;
    sincosf(k * w_, &sw, &cw);
    float rr = fmaf(cw, Ar, sw * Br);
    float ri = fmaf(cw, Ai, sw * Bi);
    float lhs = fmaf(cw * cw, Pm, fmaf(2.f * cw * sw, Qm, sw * sw * Rm));
    xr[v] = rr / lhs;
    xi[v] = sign * ri / lhs;
  }
  __syncthreads();
  int b = threadIdx.x;
  if (b < NP) {
    int xb = (b + 120) % NF;
    float stc, sts;
    sincosf(TWO_PI * (float)xb / (float)NF, &sts, &stc);
    float c = 1.f, s = 0.f, accR = 0.f, accI = 0.f;
#pragma unroll 4
    for (int vv = 0; vv < NF; ++vv) {
      float xrv = xr[vv], xiv = xi[vv];
      accR = fmaf(xrv, c, accR); accR = fmaf(-xiv, s, accR);
      accI = fmaf(xrv, s, accI); accI = fmaf(xiv, c, accI);
      rot(c, s, stc, sts);
    }
    G[(size_t)u * NP + b] = make_float2(accR, accI);
  }
}

// K6: ifft_y — out[a][b] = Re(sum_u G[u][b] e^{+2pi i ya u/160})/25600
__global__ __launch_bounds__(64) void k_ifft_y(const float2* __restrict__ G,
                                               float* __restrict__ out) {
  int idx = blockIdx.x * 64 + threadIdx.x;    // 6400
  int b = idx % NP;
  int a = idx / NP;
  int ya = (a + 120) % NF;
  float stc, sts;
  sincosf(TWO_PI * (float)ya / (float)NF, &sts, &stc);
  float c = 1.f, s = 0.f, accR = 0.f;
#pragma unroll 4
  for (int u = 0; u < NF; ++u) {
    float2 g = G[(size_t)u * NP + b];
    accR = fmaf(g.x, c, accR);
    accR = fmaf(-g.y, s, accR);
    rot(c, s, stc, sts);
  }
  out[idx] = accR * (1.f / 25600.f);
}

extern "C" void kernel_launch(void* const* d_in, const int* in_sizes, int n_in,
                              void* d_out, int out_size, void* d_ws, size_t ws_size,
                              hipStream_t stream) {
  (void)in_sizes; (void)n_in; (void)out_size; (void)ws_size;
  const float* patch  = (const float*)d_in[0];
  const float* gw     = (const float*)d_in[1];
  const float* delays = (const float*)d_in[2];
  const float* theta  = (const float*)d_in[4];
  const float* kloss  = (const float*)d_in[5];
  const float* cand   = (const float*)d_in[6];
  float* out = (float*)d_out;

  char* ws = (char*)d_ws;
  size_t off = 0;
  float2* Y = (float2*)(ws + off);      off += (size_t)ND * NF * NV * 8;     // 6,635,520
  float2* T = (float2*)(ws + off);      off += (size_t)ND * NP * NV * 8;     // 3,317,760
  float4* Yk4 = (float4*)(ws + off);    off += (size_t)(ND / 4) * NPIXP * 16;// 3,342,336
  float* prm = (float*)(ws + off);      off += (size_t)NPRM * NPIXP * 4;     //   887,808
  float* partial = (float*)(ws + off);  off += (size_t)NJ * NC * 4;          //   104,448
  float2* G = (float2*)(ws + off);      off += (size_t)NF * NP * 8;          //   102,400

  hipLaunchKernelGGL(k_fft_x, dim3((ND * NP * NV) / 256), dim3(256), 0, stream, patch, gw, T);
  hipLaunchKernelGGL(k_fft_y, dim3((ND * 40 * NV) / 256), dim3(256), 0, stream, T, Y);
  hipLaunchKernelGGL(k_prep, dim3(NXBLK), dim3(256), 0, stream, Y, delays, kloss, theta, Yk4, prm);
  hipLaunchKernelGGL(k_cand, dim3(NXBLK, NC / CPB), dim3(256), 0, stream, Yk4, prm, cand, partial);
  hipLaunchKernelGGL(k_amin_ifftu, dim3(NF), dim3(256), 0, stream, partial, prm, cand, out, G);
  hipLaunchKernelGGL(k_ifft_y, dim3(100), dim3(64), 0, stream, G, out);
}

// Round 9
// 100.344 us; speedup vs baseline: 3.4510x; 1.0283x over previous
//
#include <hip/hip_runtime.h>

#define NF 160
#define NP 80
#define ND 64
#define NC 512
#define NV 81                  // stored v columns 0..80 (Hermitian half)
#define NPIXH (NF*NV)          // 12960
#define NPIXP 13056            // padded to 51*256
#define NXBLK 51
#define NJ NXBLK               // partial rows (reduced in-block)
#define CPB 16                 // candidates per block
#define CT 8                   // candidate register tile (2 tiles per block)
#define TWO_PI 6.283185307179586f

// per-pixel precomputed parameter slots
#define IP_AR 0
#define IP_AI 1
#define IP_BR 2
#define IP_BI 3
#define IP_P  4
#define IP_Q  5
#define IP_R  6
#define IP_C2T 7
#define IP_S2T 8
#define IP_K  9
#define IP_CD0 10
#define IP_SD0 11
#define IP_CD1 12
#define IP_SD1 13
#define IP_TCD 14
#define IP_S0 15
#define IP_W  16
#define NPRM 17

__device__ __forceinline__ void rot(float& c, float& s, float stc, float sts) {
  float t1 = s * sts;
  float t2 = s * stc;
  float cn = fmaf(c, stc, -t1);
  s = fmaf(c, sts, t2);
  c = cn;
}

__device__ __forceinline__ void start_i_pow(int n, float& c, float& s) {
  switch (n & 3) {
    case 0: c = 1.f; s = 0.f; break;
    case 1: c = 0.f; s = 1.f; break;
    case 2: c = -1.f; s = 0.f; break;
    default: c = 0.f; s = -1.f; break;
  }
}

// K1: T[d][a][v] = sum_b yw[d,a,b] * e^{-2pi i v (b-40)/160}, v in 0..80
__global__ __launch_bounds__(256) void k_fft_x(const float* __restrict__ patch,
                                               const float* __restrict__ gw,
                                               float2* __restrict__ T) {
  int idx = blockIdx.x * 256 + threadIdx.x;   // ND*NP*NV = 414720
  int v = idx % NV;
  int a = (idx / NV) % NP;
  int d = idx / (NV * NP);
  float c, s;
  start_i_pow(v, c, s);
  float stc, sts;
  sincosf(-TWO_PI * (float)v / (float)NF, &sts, &stc);
  const float* prow = patch + (size_t)(d * NP + a) * NP;
  const float* grow = gw + a * NP;
  float accR = 0.f, accI = 0.f;
#pragma unroll 4
  for (int b = 0; b < NP; ++b) {
    float f = prow[b] * grow[b];
    accR = fmaf(f, c, accR);
    accI = fmaf(f, s, accI);
    rot(c, s, stc, sts);
  }
  T[idx] = make_float2(accR, accI);
}

// K2: Y[d][u][v] = sum_a T[d][a][v] * e^{-2pi i u (a-40)/160}
__global__ __launch_bounds__(256) void k_fft_y(const float2* __restrict__ T,
                                               float2* __restrict__ Y) {
  int idx = blockIdx.x * 256 + threadIdx.x;   // 64*40*81 = 207360
  int v = idx % NV;
  int ug = (idx / NV) % 40;
  int d = idx / (NV * 40);
  float c[4], s[4], aR[4], aI[4], stc[4], sts[4];
#pragma unroll
  for (int j = 0; j < 4; ++j) {
    int u = ug * 4 + j;
    start_i_pow(u, c[j], s[j]);
    sincosf(-TWO_PI * (float)u / (float)NF, &sts[j], &stc[j]);
    aR[j] = 0.f; aI[j] = 0.f;
  }
  const float2* Tb = T + (size_t)(d * NP) * NV + v;
#pragma unroll 4
  for (int a = 0; a < NP; ++a) {
    float2 t = Tb[(size_t)a * NV];
#pragma unroll
    for (int j = 0; j < 4; ++j) {
      aR[j] = fmaf(t.x, c[j], aR[j]);
      aR[j] = fmaf(-t.y, s[j], aR[j]);
      aI[j] = fmaf(t.x, s[j], aI[j]);
      aI[j] = fmaf(t.y, c[j], aI[j]);
      rot(c[j], s[j], stc[j], sts[j]);
    }
  }
#pragma unroll
  for (int j = 0; j < 4; ++j) {
    int u = ug * 4 + j;
    Y[((size_t)d * NF + u) * NV + v] = make_float2(aR[j], aI[j]);
  }
}

// K3: per-pixel candidate-independent moments; Yk4 packing for dual chains
__global__ __launch_bounds__(256) void k_prep(const float2* __restrict__ Y,
                                              const float* __restrict__ delays,
                                              const float* __restrict__ kloss,
                                              const float* __restrict__ theta,
                                              float4* __restrict__ Yk4,
                                              float* __restrict__ prm) {
  int p = blockIdx.x * 256 + threadIdx.x;     // 51*256 = 13056
  if (p >= NPIXH) {
#pragma unroll
    for (int jj = 0; jj < ND / 4; ++jj)
      Yk4[(size_t)jj * NPIXP + p] = make_float4(0.f, 0.f, 0.f, 0.f);
    prm[IP_AR * NPIXP + p] = 0.f;  prm[IP_AI * NPIXP + p] = 0.f;
    prm[IP_BR * NPIXP + p] = 0.f;  prm[IP_BI * NPIXP + p] = 0.f;
    prm[IP_P * NPIXP + p] = 1.f;   prm[IP_Q * NPIXP + p] = 0.f;
    prm[IP_R * NPIXP + p] = 1.f;   prm[IP_C2T * NPIXP + p] = 0.f;
    prm[IP_S2T * NPIXP + p] = 0.f; prm[IP_K * NPIXP + p] = 0.f;
    prm[IP_CD0 * NPIXP + p] = 1.f; prm[IP_SD0 * NPIXP + p] = 0.f;
    prm[IP_CD1 * NPIXP + p] = 1.f; prm[IP_SD1 * NPIXP + p] = 0.f;
    prm[IP_TCD * NPIXP + p] = 2.f; prm[IP_S0 * NPIXP + p] = 0.f;
    prm[IP_W * NPIXP + p] = 0.f;
    return;
  }
  int u = p / NV, v = p % NV;
  float k = kloss[u * NF + v];
  float th = theta[((u + 80) % NF) * NF + ((v + 80) % NF)];
  float c2t = cosf(2.f * th), s2t = sinf(2.f * th);
  float w;
  if (v == 0 || v == 80) {
    if (u == 0 || u == 80) w = 1.f;
    else if (u < 80) w = 2.f;
    else w = 0.f;
  } else w = 2.f;
  float d0 = delays[0], d1 = delays[1];
  float sd0f, cd0f;
  sincosf(k * d0, &sd0f, &cd0f);
  float stc, sts;
  sincosf(k * (d1 - d0), &sts, &stc);
  float tcd = 2.f * stc;
  float cd = cd0f, sd = sd0f;
  float cd1s = 0.f, sd1s = 0.f;
  float Ar = 0.f, Ai = 0.f, Br = 0.f, Bi = 0.f, Pm = 0.f, Qm = 0.f, Rm = 0.f, S0 = 0.f;
  float yktmp[ND];
#pragma unroll
  for (int d = 0; d < ND; ++d) {
    if (d == 1) { cd1s = cd; sd1s = sd; }
    float2 y = Y[((size_t)d * NF + u) * NV + v];
    Ar = fmaf(y.x, cd, Ar);  Ai = fmaf(y.y, cd, Ai);
    Br = fmaf(y.x, sd, Br);  Bi = fmaf(y.y, sd, Bi);
    Pm = fmaf(cd, cd, Pm);  Qm = fmaf(cd, sd, Qm);  Rm = fmaf(sd, sd, Rm);
    float yk = sqrtf(fmaf(y.x, y.x, y.y * y.y)) * k;
    yktmp[d] = yk;
    S0 = fmaf(yk, yk, S0);
    rot(cd, sd, stc, sts);
  }
#pragma unroll
  for (int jj = 0; jj < ND / 4; ++jj)
    Yk4[(size_t)jj * NPIXP + p] = make_float4(yktmp[2 * jj], yktmp[63 - 2 * jj],
                                              yktmp[2 * jj + 1], yktmp[62 - 2 * jj]);
  prm[IP_AR * NPIXP + p] = Ar;   prm[IP_AI * NPIXP + p] = Ai;
  prm[IP_BR * NPIXP + p] = Br;   prm[IP_BI * NPIXP + p] = Bi;
  prm[IP_P * NPIXP + p] = Pm;    prm[IP_Q * NPIXP + p] = Qm;
  prm[IP_R * NPIXP + p] = Rm;    prm[IP_C2T * NPIXP + p] = c2t;
  prm[IP_S2T * NPIXP + p] = s2t; prm[IP_K * NPIXP + p] = k;
  prm[IP_CD0 * NPIXP + p] = cd0f; prm[IP_SD0 * NPIXP + p] = sd0f;
  prm[IP_CD1 * NPIXP + p] = cd1s; prm[IP_SD1 * NPIXP + p] = sd1s;
  prm[IP_TCD * NPIXP + p] = tcd; prm[IP_S0 * NPIXP + p] = S0;
  prm[IP_W * NPIXP + p] = w;
}

// K4: hot kernel — candidate-tiled: d streams innermost, one Yk4 load feeds
// CT=8 candidates' Chebyshev chains (loop-carried state = 7 regs/candidate).
__global__ __launch_bounds__(256, 3) void k_cand(const float4* __restrict__ Yk4,
                                                 const float* __restrict__ prm,
                                                 const float* __restrict__ cand,
                                                 float* __restrict__ partial) {
  int p = blockIdx.x * 256 + threadIdx.x;     // NXBLK=51 blocks in x
  int c0 = blockIdx.y * CPB;
  float Ar = prm[IP_AR * NPIXP + p], Ai = prm[IP_AI * NPIXP + p];
  float Br = prm[IP_BR * NPIXP + p], Bi = prm[IP_BI * NPIXP + p];
  float Pm = prm[IP_P * NPIXP + p], Qm = prm[IP_Q * NPIXP + p], Rm = prm[IP_R * NPIXP + p];
  float c2t = prm[IP_C2T * NPIXP + p], s2t = prm[IP_S2T * NPIXP + p];
  float k = prm[IP_K * NPIXP + p];
  float cd0 = prm[IP_CD0 * NPIXP + p], sd0 = prm[IP_SD0 * NPIXP + p];
  float cd1 = prm[IP_CD1 * NPIXP + p], sd1 = prm[IP_SD1 * NPIXP + p];
  float tcd = prm[IP_TCD * NPIXP + p], S0 = prm[IP_S0 * NPIXP + p];
  float wgt = prm[IP_W * NPIXP + p];
  int wid = threadIdx.x >> 6;
  int lane = threadIdx.x & 63;
  __shared__ float sdata[CPB][4];
  float4 yk0 = Yk4[p];                        // (yk[0], yk[63], yk[1], yk[62])
  for (int t = 0; t < CPB / CT; ++t) {
    int cb = c0 + t * CT;
    float A0[CT], A1[CT], B0[CT], B1[CT], M[CT], F0[CT], F1[CT];
#pragma unroll
    for (int ci = 0; ci < CT; ++ci) {
      int c = cb + ci;
      float dc = cand[c * 3 + 0], xx = cand[c * 3 + 1], yy = cand[c * 3 + 2];
      float w_ = fmaf(xx, c2t, fmaf(yy, s2t, dc));
      float sw, cw;
      __sincosf(k * w_, &sw, &cw);
      float rr = fmaf(cw, Ar, sw * Br);
      float ri = fmaf(cw, Ai, sw * Bi);
      float lhs = fmaf(cw * cw, Pm, fmaf(2.f * cw * sw, Qm, sw * sw * Rm));
      float rabs = __builtin_amdgcn_sqrtf(fmaf(rr, rr, ri * ri));
      float rl = __builtin_amdgcn_rcpf(lhs);
      float e = fmaf(-lhs, rl, 1.f);
      rl = fmaf(rl, e, rl);                   // refined 1/lhs
      float kX = k * rabs * rl;
      F0[ci] = fmaf(kX * kX, lhs, S0);        // contrib = F0 + F1*M
      F1[ci] = -2.f * kX;
      float t0 = cd0 * cw, u0 = sd0 * sw;
      float t1 = cd1 * cw, u1 = sd1 * sw;
      A0[ci] = t0 + u0;  B0[ci] = t0 - u0;    // cos(k d0 -/+ kw)
      A1[ci] = t1 + u1;  B1[ci] = t1 - u1;    // cos(k d1 -/+ kw)
      float m = yk0.x * fabsf(A0[ci]);
      m = fmaf(yk0.z, fabsf(A1[ci]), m);
      m = fmaf(yk0.y, fabsf(B0[ci]), m);
      m = fmaf(yk0.w, fabsf(B1[ci]), m);
      M[ci] = m;
    }
#pragma unroll
    for (int jj = 1; jj < ND / 4; ++jj) {
      float4 yk = Yk4[(size_t)jj * NPIXP + p];
#pragma unroll
      for (int ci = 0; ci < CT; ++ci) {
        float An = fmaf(tcd, A1[ci], -A0[ci]);      // A_{2jj}
        float Bn = fmaf(tcd, B1[ci], -B0[ci]);
        float m = fmaf(yk.x, fabsf(An), M[ci]);
        m = fmaf(yk.y, fabsf(Bn), m);
        float An2 = fmaf(tcd, An, -A1[ci]);         // A_{2jj+1}
        float Bn2 = fmaf(tcd, Bn, -B1[ci]);
        m = fmaf(yk.z, fabsf(An2), m);
        m = fmaf(yk.w, fabsf(Bn2), m);
        M[ci] = m;
        A0[ci] = An;  A1[ci] = An2;
        B0[ci] = Bn;  B1[ci] = Bn2;
      }
    }
#pragma unroll
    for (int ci = 0; ci < CT; ++ci) {
      float contrib = fmaf(F1[ci], M[ci], F0[ci]) * wgt;
      for (int off = 32; off > 0; off >>= 1) contrib += __shfl_xor(contrib, off);
      if (lane == 0) sdata[t * CT + ci][wid] = contrib;
    }
  }
  __syncthreads();
  if (threadIdx.x < CPB) {
    int ci = threadIdx.x;
    float s = (sdata[ci][0] + sdata[ci][1]) + (sdata[ci][2] + sdata[ci][3]);
    partial[(size_t)blockIdx.x * NC + c0 + ci] = s;
  }
}

// K5: fused redundant argmin (per block) + ifft_u row DFT (blocks 0..159)
__global__ __launch_bounds__(256) void k_amin_ifftu(const float* __restrict__ partial,
                                                    const float* __restrict__ prm,
                                                    const float* __restrict__ cand,
                                                    float* __restrict__ out,
                                                    float2* __restrict__ G) {
  __shared__ float sl[256];
  __shared__ int si[256];
  __shared__ float xr[NF], xi[NF];
  int c1 = threadIdx.x, c2 = threadIdx.x + 256;
  float s1 = 0.f, s2 = 0.f;
#pragma unroll
  for (int j = 0; j < NJ; ++j) {
    s1 += partial[(size_t)j * NC + c1];
    s2 += partial[(size_t)j * NC + c2];
  }
  float l; int i;
  if (s2 < s1) { l = s2; i = c2; } else { l = s1; i = c1; }
  sl[threadIdx.x] = l; si[threadIdx.x] = i;
  __syncthreads();
  for (int off = 128; off > 0; off >>= 1) {
    if (threadIdx.x < off) {
      float l2 = sl[threadIdx.x + off]; int i2 = si[threadIdx.x + off];
      if (l2 < sl[threadIdx.x] || (l2 == sl[threadIdx.x] && i2 < si[threadIdx.x])) {
        sl[threadIdx.x] = l2; si[threadIdx.x] = i2;
      }
    }
    __syncthreads();
  }
  int bi = si[0];
  if (blockIdx.x == 0 && threadIdx.x == 0) {
    out[6400] = cand[bi * 3 + 0];
    out[6401] = cand[bi * 3 + 1];
    out[6402] = cand[bi * 3 + 2];
    out[6403] = sl[0] * (1.f / 1638400.f);
  }
  int u = blockIdx.x;
  float dc = cand[bi * 3 + 0], xx = cand[bi * 3 + 1], yy = cand[bi * 3 + 2];
  int v = threadIdx.x;
  if (v < NF) {
    float sign = 1.f;
    int ph;
    if (v <= 80) {
      ph = u * NV + v;
    } else {
      int u2 = (NF - u) % NF;
      ph = u2 * NV + (NF - v);
      sign = -1.f;
    }
    float Ar = prm[IP_AR * NPIXP + ph], Ai = prm[IP_AI * NPIXP + ph];
    float Br = prm[IP_BR * NPIXP + ph], Bi = prm[IP_BI * NPIXP + ph];
    float Pm = prm[IP_P * NPIXP + ph], Qm = prm[IP_Q * NPIXP + ph], Rm = prm[IP_R * NPIXP + ph];
    float c2t = prm[IP_C2T * NPIXP + ph], s2t = prm[IP_S2T * NPIXP + ph];
    float k = prm[IP_K * NPIXP + ph];
    float w_ = fmaf(xx, c2t, fmaf(yy, s2t, dc));
    float sw, cw;
    sincosf(k * w_, &sw, &cw);
    float rr = fmaf(cw, Ar, sw * Br);
    float ri = fmaf(cw, Ai, sw * Bi);
    float lhs = fmaf(cw * cw, Pm, fmaf(2.f * cw * sw, Qm, sw * sw * Rm));
    xr[v] = rr / lhs;
    xi[v] = sign * ri / lhs;
  }
  __syncthreads();
  int b = threadIdx.x;
  if (b < NP) {
    int xb = (b + 120) % NF;
    float stc, sts;
    sincosf(TWO_PI * (float)xb / (float)NF, &sts, &stc);
    float c = 1.f, s = 0.f, accR = 0.f, accI = 0.f;
#pragma unroll 4
    for (int vv = 0; vv < NF; ++vv) {
      float xrv = xr[vv], xiv = xi[vv];
      accR = fmaf(xrv, c, accR); accR = fmaf(-xiv, s, accR);
      accI = fmaf(xrv, s, accI); accI = fmaf(xiv, c, accI);
      rot(c, s, stc, sts);
    }
    G[(size_t)u * NP + b] = make_float2(accR, accI);
  }
}

// K6: ifft_y — out[a][b] = Re(sum_u G[u][b] e^{+2pi i ya u/160})/25600
__global__ __launch_bounds__(64) void k_ifft_y(const float2* __restrict__ G,
                                               float* __restrict__ out) {
  int idx = blockIdx.x * 64 + threadIdx.x;    // 6400
  int b = idx % NP;
  int a = idx / NP;
  int ya = (a + 120) % NF;
  float stc, sts;
  sincosf(TWO_PI * (float)ya / (float)NF, &sts, &stc);
  float c = 1.f, s = 0.f, accR = 0.f;
#pragma unroll 4
  for (int u = 0; u < NF; ++u) {
    float2 g = G[(size_t)u * NP + b];
    accR = fmaf(g.x, c, accR);
    accR = fmaf(-g.y, s, accR);
    rot(c, s, stc, sts);
  }
  out[idx] = accR * (1.f / 25600.f);
}

extern "C" void kernel_launch(void* const* d_in, const int* in_sizes, int n_in,
                              void* d_out, int out_size, void* d_ws, size_t ws_size,
                              hipStream_t stream) {
  (void)in_sizes; (void)n_in; (void)out_size; (void)ws_size;
  const float* patch  = (const float*)d_in[0];
  const float* gw     = (const float*)d_in[1];
  const float* delays = (const float*)d_in[2];
  const float* theta  = (const float*)d_in[4];
  const float* kloss  = (const float*)d_in[5];
  const float* cand   = (const float*)d_in[6];
  float* out = (float*)d_out;

  char* ws = (char*)d_ws;
  size_t off = 0;
  float2* Y = (float2*)(ws + off);      off += (size_t)ND * NF * NV * 8;     // 6,635,520
  float2* T = (float2*)(ws + off);      off += (size_t)ND * NP * NV * 8;     // 3,317,760
  float4* Yk4 = (float4*)(ws + off);    off += (size_t)(ND / 4) * NPIXP * 16;// 3,342,336
  float* prm = (float*)(ws + off);      off += (size_t)NPRM * NPIXP * 4;     //   887,808
  float* partial = (float*)(ws + off);  off += (size_t)NJ * NC * 4;          //   104,448
  float2* G = (float2*)(ws + off);      off += (size_t)NF * NP * 8;          //   102,400

  hipLaunchKernelGGL(k_fft_x, dim3((ND * NP * NV) / 256), dim3(256), 0, stream, patch, gw, T);
  hipLaunchKernelGGL(k_fft_y, dim3((ND * 40 * NV) / 256), dim3(256), 0, stream, T, Y);
  hipLaunchKernelGGL(k_prep, dim3(NXBLK), dim3(256), 0, stream, Y, delays, kloss, theta, Yk4, prm);
  hipLaunchKernelGGL(k_cand, dim3(NXBLK, NC / CPB), dim3(256), 0, stream, Yk4, prm, cand, partial);
  hipLaunchKernelGGL(k_amin_ifftu, dim3(NF), dim3(256), 0, stream, partial, prm, cand, out, G);
  hipLaunchKernelGGL(k_ifft_y, dim3(100), dim3(64), 0, stream, G, out);
}